// Round 5
// baseline (7555.109 us; speedup 1.0000x reference)
//
#include <hip/hip_runtime.h>
#include <hip/hip_bf16.h>
#include <math.h>

typedef __hip_bfloat16 bf16;

static __device__ __forceinline__ float b2f(bf16 x) { return __bfloat162float(x); }
static __device__ __forceinline__ bf16  f2b(float x) { return __float2bfloat16(x); }

// Polymorphic input load: isb=true -> bf16 storage, else f32 storage.
static __device__ __forceinline__ float ldin(const void* p, size_t i, bool isb) {
    return isb ? b2f(((const bf16*)p)[i]) : ((const float*)p)[i];
}

// ---------------------------------------------------------------- dtype detect
// Reads 1024 u32 words of an input tensor drawn from N(0,1). If storage is
// bf16, the low 16 bits of each word are a sane bf16 (|v| < 1e6). If storage
// is f32, the low 16 bits are mantissa garbage (~42% decode insane).
__global__ void detect_kernel(const unsigned int* __restrict__ x, float* __restrict__ flagp) {
    __shared__ int sh[64];
    int insane = 0;
    for (int i = threadIdx.x; i < 1024; i += 64) {
        unsigned int lo = (x[i] & 0xFFFFu) << 16;
        float v = __uint_as_float(lo);
        if (!(fabsf(v) <= 1e6f)) insane++;        // catches NaN/Inf too
    }
    sh[threadIdx.x] = insane;
    __syncthreads();
    if (threadIdx.x == 0) {
        int t = 0;
        for (int i = 0; i < 64; ++i) t += sh[i];
        *flagp = (t < 16) ? 1.f : 0.f;            // 1 => inputs are bf16
    }
}

// ---------------------------------------------------------------- diagnostic fill (dtype-agnostic)
__global__ void diag_fill(unsigned int* __restrict__ out, int nwords, float val) {
    int i = blockIdx.x * blockDim.x + threadIdx.x;
    if (i < nwords) {
        unsigned short h = (unsigned short)(__float_as_uint(val) >> 16); // bf16 bits of val
        out[i] = ((unsigned int)h << 16) | h;     // sane under bf16 AND f32 readback
    }
}

// ---------------------------------------------------------------- 2x2 mean pool (input -> bf16 ws)
__global__ void pool2_kernel(const void* __restrict__ in, const float* __restrict__ flg,
                             bf16* __restrict__ out, int BC, int H2, int W2) {
    bool isb = (*flg != 0.f);
    int idx = blockIdx.x * blockDim.x + threadIdx.x;
    int total = BC * H2 * W2;
    if (idx >= total) return;
    int p  = idx % (H2 * W2);
    int bc = idx / (H2 * W2);
    int h = p / W2, w = p % W2;
    int W = 2 * W2;
    size_t base = (size_t)bc * (4 * H2 * W2);
    float s = ldin(in, base + (2*h)*W + 2*w, isb)     + ldin(in, base + (2*h)*W + 2*w + 1, isb)
            + ldin(in, base + (2*h+1)*W + 2*w, isb)   + ldin(in, base + (2*h+1)*W + 2*w + 1, isb);
    out[idx] = f2b(0.25f * s);
}

// ---------------------------------------------------------------- direct conv3x3, zero-pad SAME
// virtual concat of in1 (C1 ch) and in2 (C2 ch). modeX: 1 = external input (use
// flag dtype), 0 = workspace (always bf16). act: 0 none, 1 relu, 2 prelu.
__global__ void conv3x3_kernel(const void* __restrict__ in1, int C1, int mode1,
                               const void* __restrict__ in2, int C2, int mode2,
                               const void* __restrict__ wt,
                               const void* __restrict__ bias,
                               const void* __restrict__ alpha,
                               const float* __restrict__ flg,
                               bf16* __restrict__ out,
                               int H, int W, int Cout, int act) {
    extern __shared__ float wsm[];                 // (C1+C2)*9 staged weights (f32)
    bool isb = (*flg != 0.f);
    bool b1 = mode1 ? isb : true;
    bool b2 = mode2 ? isb : true;
    const int Cin = C1 + C2;
    const int b  = blockIdx.z;
    const int co = blockIdx.y;
    for (int i = threadIdx.x; i < Cin * 9; i += blockDim.x)
        wsm[i] = ldin(wt, (size_t)co * Cin * 9 + i, isb);
    __syncthreads();

    int p = blockIdx.x * blockDim.x + threadIdx.x;
    if (p >= H * W) return;
    int h = p / W, w = p % W;

    float acc = ldin(bias, co, isb);
    for (int ci = 0; ci < Cin; ++ci) {
        const void* src; size_t base; bool sb;
        if (ci < C1) { src = in1; base = (size_t)(b * C1 + ci) * H * W;        sb = b1; }
        else         { src = in2; base = (size_t)(b * C2 + (ci - C1)) * H * W; sb = b2; }
        const float* wrow = wsm + ci * 9;
        #pragma unroll
        for (int kh = 0; kh < 3; ++kh) {
            int ih = h + kh - 1;
            if (ih < 0 || ih >= H) continue;
            #pragma unroll
            for (int kk = 0; kk < 3; ++kk) {
                int iw = w + kk - 1;
                if (iw < 0 || iw >= W) continue;
                acc = fmaf(ldin(src, base + (size_t)ih * W + iw, sb), wrow[kh * 3 + kk], acc);
            }
        }
    }
    if (act == 1) {
        acc = fmaxf(acc, 0.f);
    } else if (act == 2) {
        float a = ldin(alpha, co, isb);
        acc = acc >= 0.f ? acc : a * acc;
    }
    out[(size_t)(b * Cout + co) * H * W + p] = f2b(acc);
}

// ---------------------------------------------------------------- fused CAUN tail
// 1x1 mask conv (36 rows / channel) + softmax over 9 + neighbor blend + scrambled scatter.
// f: bf16 workspace. xlow: modex as above. kw/kb: external inputs.
__global__ void caun_kernel(const bf16* __restrict__ f,
                            const void* __restrict__ xlow, int modex,
                            const void* __restrict__ kw,
                            const void* __restrict__ kb,
                            const float* __restrict__ flg,
                            bf16* __restrict__ out,
                            int C, int K, int H, int W) {
    extern __shared__ float sm[];           // 36*K weights + 36 bias
    bool isb = (*flg != 0.f);
    bool bx = modex ? isb : true;
    float* kws = sm;
    float* kbs = sm + 36 * K;
    int bc = blockIdx.y;
    int b = bc / C, c = bc % C;
    for (int i = threadIdx.x; i < 36 * K; i += blockDim.x)
        kws[i] = ldin(kw, (size_t)(c * 36) * K + i, isb);
    for (int i = threadIdx.x; i < 36; i += blockDim.x)
        kbs[i] = ldin(kb, c * 36 + i, isb);
    __syncthreads();

    int p = blockIdx.x * blockDim.x + threadIdx.x;
    if (p >= H * W) return;
    int h = p / W, w = p % W;

    float logits[36];
    #pragma unroll
    for (int j = 0; j < 36; ++j) logits[j] = kbs[j];

    const bf16* fp = f + (size_t)b * K * H * W + p;
    for (int k = 0; k < K; ++k) {
        float fv = b2f(fp[(size_t)k * H * W]);
        const float* kr = kws + k;
        #pragma unroll
        for (int j = 0; j < 36; ++j)
            logits[j] = fmaf(fv, kr[j * K], logits[j]);
    }

    float neigh[9];
    size_t xbase = (size_t)(b * C + c) * H * W;
    #pragma unroll
    for (int n = 0; n < 9; ++n) {
        int ih = h + n / 3 - 1; ih = min(max(ih, 0), H - 1);
        int iw = w + n % 3 - 1; iw = min(max(iw, 0), W - 1);
        neigh[n] = ldin(xlow, xbase + (size_t)ih * W + iw, bx);
    }

    bf16* op = out + (size_t)(b * C + c) * 4 * H * W;
    #pragma unroll
    for (int u = 0; u < 2; ++u) {
        #pragma unroll
        for (int v = 0; v < 2; ++v) {
            int g = u * 2 + v;
            float mx = -1e30f;
            #pragma unroll
            for (int n = 0; n < 9; ++n) mx = fmaxf(mx, logits[n * 4 + g]);
            float se = 0.f, acc = 0.f;
            #pragma unroll
            for (int n = 0; n < 9; ++n) {
                float e = expf(logits[n * 4 + g] - mx);
                se += e;
                acc = fmaf(e, neigh[n], acc);
            }
            int L = ((w * 2 + v) * H + h) * 2 + u;   // torch permute(0,1,5,3,4,2)
            op[L] = f2b(acc / se);
        }
    }
}

// ---------------------------------------------------------------- memory bank: row-l2norm of mem
__global__ void memnorm_kernel(const void* __restrict__ mem, const float* __restrict__ flg,
                               float* __restrict__ mn) {
    bool isb = (*flg != 0.f);
    int s = threadIdx.x;          // 64 slots
    float v[32];
    float ss = 0.f;
    #pragma unroll
    for (int c = 0; c < 32; ++c) { v[c] = ldin(mem, s * 32 + c, isb); ss += v[c] * v[c]; }
    float inv = 1.f / fmaxf(sqrtf(ss), 1e-12f);
    #pragma unroll
    for (int c = 0; c < 32; ++c) mn[s * 32 + c] = v[c] * inv;
}

// ---------------------------------------------------------------- memory fusion (in place, [B,32,H,W] bf16 ws)
__global__ void memfuse_kernel(bf16* __restrict__ x, const float* __restrict__ mn, int HW) {
    __shared__ float mns[64 * 32];
    for (int i = threadIdx.x; i < 64 * 32; i += blockDim.x) mns[i] = mn[i];
    __syncthreads();
    int idx = blockIdx.x * blockDim.x + threadIdx.x;   // over B*HW
    int b = idx / HW, p = idx % HW;
    bf16* xp = x + (size_t)b * 32 * HW + p;

    float feat[32];
    float ss = 0.f;
    #pragma unroll
    for (int c = 0; c < 32; ++c) { feat[c] = b2f(xp[(size_t)c * HW]); ss += feat[c] * feat[c]; }
    float inv = 1.f / fmaxf(sqrtf(ss), 1e-12f);

    float d[64];
    float mx = -1e30f;
    for (int s = 0; s < 64; ++s) {
        float acc = 0.f;
        const float* mr = mns + s * 32;
        #pragma unroll
        for (int c = 0; c < 32; ++c) acc = fmaf(feat[c] * inv, mr[c], acc);
        d[s] = acc;
        mx = fmaxf(mx, acc);
    }
    float se = 0.f;
    for (int s = 0; s < 64; ++s) { d[s] = expf(d[s] - mx); se += d[s]; }
    float rse = 1.f / se;
    #pragma unroll
    for (int c = 0; c < 32; ++c) {
        float acc = 0.f;
        for (int s = 0; s < 64; ++s) acc = fmaf(d[s], mns[s * 32 + c], acc);
        xp[(size_t)c * HW] = f2b(feat[c] + acc * rse);
    }
}

// ---------------------------------------------------------------- final 1x1 conv 32 -> 2, dtype-matched out
__global__ void final1x1_kernel(const bf16* __restrict__ x,
                                const void* __restrict__ fw, const void* __restrict__ fb,
                                const float* __restrict__ flg,
                                void* __restrict__ out, int HW) {
    bool isb = (*flg != 0.f);
    int idx = blockIdx.x * blockDim.x + threadIdx.x;   // over B*HW
    int b = idx / HW, p = idx % HW;
    const bf16* xp = x + (size_t)b * 32 * HW + p;
    float a0 = ldin(fb, 0, isb), a1 = ldin(fb, 1, isb);
    #pragma unroll
    for (int c = 0; c < 32; ++c) {
        float v = b2f(xp[(size_t)c * HW]);
        a0 = fmaf(v, ldin(fw, c, isb), a0);
        a1 = fmaf(v, ldin(fw, 32 + c, isb), a1);
    }
    size_t i0 = (size_t)b * 2 * HW + p;
    size_t i1 = i0 + HW;
    if (isb) { ((bf16*)out)[i0] = f2b(a0); ((bf16*)out)[i1] = f2b(a1); }
    else     { ((float*)out)[i0] = a0;     ((float*)out)[i1] = a1; }
}

// ================================================================ host
extern "C" void kernel_launch(void* const* d_in, const int* in_sizes, int n_in,
                              void* d_out, int out_size, void* d_ws, size_t ws_size,
                              hipStream_t stream) {
    const void* x0_0 = d_in[0];
    const void* x1_0 = d_in[1];
    const void* x2_0 = d_in[2];
    const void* x3_0 = d_in[3];
    const void* c3_w1 = d_in[4];  const void* c3_b1 = d_in[5];  const void* c3_a1 = d_in[6];
    const void* c3_w2 = d_in[7];  const void* c3_b2 = d_in[8];  const void* c3_a2 = d_in[9];
    const void* c3_kw = d_in[10]; const void* c3_kb = d_in[11];
    const void* c2_w1 = d_in[12]; const void* c2_b1 = d_in[13]; const void* c2_a1 = d_in[14];
    const void* c2_w2 = d_in[15]; const void* c2_b2 = d_in[16]; const void* c2_a2 = d_in[17];
    const void* c2_kw = d_in[18]; const void* c2_kb = d_in[19];
    const void* c1_w1 = d_in[20]; const void* c1_b1 = d_in[21]; const void* c1_a1 = d_in[22];
    const void* c1_w2 = d_in[23]; const void* c1_b2 = d_in[24]; const void* c1_a2 = d_in[25];
    const void* c1_kw = d_in[26]; const void* c1_kb = d_in[27];
    const void* b21_w1 = d_in[28]; const void* b21_b1 = d_in[29];
    const void* b21_w2 = d_in[30]; const void* b21_b2 = d_in[31];
    const void* b12_w1 = d_in[32]; const void* b12_b1 = d_in[33];
    const void* b12_w2 = d_in[34]; const void* b12_b2 = d_in[35];
    const void* b03_w1 = d_in[36]; const void* b03_b1 = d_in[37];
    const void* b03_w2 = d_in[38]; const void* b03_b2 = d_in[39];
    const void* fin_w = d_in[40];  const void* fin_b = d_in[41];
    const void* memw  = d_in[42];
    (void)in_sizes; (void)n_in;

    const int TB = 256;
    auto blocks = [](int n) { return (n + 255) / 256; };

    // 24 MiB arena + 64 KiB tail for mn/flag. Round 4 proved ws_size >= 24 MiB.
    const size_t NEED = 25165824 + 65536;
    if (ws_size < NEED) {
        diag_fill<<<blocks(out_size / 2), TB, 0, stream>>>(
            (unsigned int*)d_out, out_size / 2, (float)ws_size);
        return;
    }
    size_t tail = (ws_size - 65536) & ~(size_t)255;
    float* mn  = (float*)((char*)d_ws + tail);          // 8 KB
    float* flg = (float*)((char*)d_ws + tail + 8192);   // 4 B

    // 24 MiB arena, hand-verified live-range plan (offsets in bf16 elements):
    bf16* A = (bf16*)d_ws;
    bf16* x3up  = A + 0;
    bf16* ctx3p = A + 2097152;
    bf16* f3a   = A + 2359296;
    bf16* f3b   = A + 2621440;
    bf16* t2a   = A + 2097152;
    bf16* x2_1  = A + 0;
    bf16* ctx2  = A + 1048576;
    bf16* f2a   = A + 1572864;
    bf16* f2b   = A + 2097152;
    bf16* x2up  = A + 2359296;
    bf16* t1a   = A + 0;
    bf16* x1_2  = A + 10485760;
    bf16* ctx1  = A + 4194304;
    bf16* f1a   = A + 5242880;
    bf16* f1b   = A + 9437184;
    bf16* x1up  = A + 0;
    bf16* t0a   = A + 8388608;
    bf16* x0_3  = A + 0;

    // ---- dtype detection (writes flg)
    detect_kernel<<<1, 64, 0, stream>>>((const unsigned int*)x0_0, flg);

    // ---- caun3: x3_0 [2,256,32,32], ctx = pool(x2_0) -> [2,128,32,32]
    pool2_kernel<<<blocks(262144), TB, 0, stream>>>(x2_0, flg, ctx3p, 256, 32, 32);
    conv3x3_kernel<<<dim3(4, 128, 2), TB, 128 * 9 * 4, stream>>>(
        ctx3p, 128, 0, nullptr, 0, 0, c3_w1, c3_b1, c3_a1, flg, f3a, 32, 32, 128, 2);
    conv3x3_kernel<<<dim3(4, 64, 2), TB, 128 * 9 * 4, stream>>>(
        f3a, 128, 0, nullptr, 0, 0, c3_w2, c3_b2, c3_a2, flg, f3b, 32, 32, 64, 2);
    caun_kernel<<<dim3(4, 512), TB, (36 * 64 + 36) * 4, stream>>>(
        f3b, x3_0, 1, c3_kw, c3_kb, flg, x3up, 256, 64, 32, 32);

    // ---- block21: cat(x2_0 [128], x3up [256]) -> 128 -> 128 @64x64
    conv3x3_kernel<<<dim3(16, 128, 2), TB, 384 * 9 * 4, stream>>>(
        x2_0, 128, 1, x3up, 256, 0, b21_w1, b21_b1, nullptr, flg, t2a, 64, 64, 128, 1);
    conv3x3_kernel<<<dim3(16, 128, 2), TB, 128 * 9 * 4, stream>>>(
        t2a, 128, 0, nullptr, 0, 0, b21_w2, b21_b2, nullptr, flg, x2_1, 64, 64, 128, 1);

    // ---- caun2: x2_1 [2,128,64,64], ctx = pool(x1_0) -> [2,64,64,64]
    pool2_kernel<<<blocks(524288), TB, 0, stream>>>(x1_0, flg, ctx2, 128, 64, 64);
    conv3x3_kernel<<<dim3(16, 64, 2), TB, 64 * 9 * 4, stream>>>(
        ctx2, 64, 0, nullptr, 0, 0, c2_w1, c2_b1, c2_a1, flg, f2a, 64, 64, 64, 2);
    conv3x3_kernel<<<dim3(16, 32, 2), TB, 64 * 9 * 4, stream>>>(
        f2a, 64, 0, nullptr, 0, 0, c2_w2, c2_b2, c2_a2, flg, f2b, 64, 64, 32, 2);
    caun_kernel<<<dim3(16, 256), TB, (36 * 32 + 36) * 4, stream>>>(
        f2b, x2_1, 0, c2_kw, c2_kb, flg, x2up, 128, 32, 64, 64);

    // ---- block12: cat(x1_0 [64], x2up [128]) -> 64 -> 64 @128x128
    conv3x3_kernel<<<dim3(64, 64, 2), TB, 192 * 9 * 4, stream>>>(
        x1_0, 64, 1, x2up, 128, 0, b12_w1, b12_b1, nullptr, flg, t1a, 128, 128, 64, 1);
    conv3x3_kernel<<<dim3(64, 64, 2), TB, 64 * 9 * 4, stream>>>(
        t1a, 64, 0, nullptr, 0, 0, b12_w2, b12_b2, nullptr, flg, x1_2, 128, 128, 64, 1);

    // ---- caun1: x1_2 [2,64,128,128], ctx = pool(x0_0) -> [2,32,128,128]
    pool2_kernel<<<blocks(1048576), TB, 0, stream>>>(x0_0, flg, ctx1, 64, 128, 128);
    conv3x3_kernel<<<dim3(64, 32, 2), TB, 32 * 9 * 4, stream>>>(
        ctx1, 32, 0, nullptr, 0, 0, c1_w1, c1_b1, c1_a1, flg, f1a, 128, 128, 32, 2);
    conv3x3_kernel<<<dim3(64, 16, 2), TB, 32 * 9 * 4, stream>>>(
        f1a, 32, 0, nullptr, 0, 0, c1_w2, c1_b2, c1_a2, flg, f1b, 128, 128, 16, 2);
    caun_kernel<<<dim3(64, 128), TB, (36 * 16 + 36) * 4, stream>>>(
        f1b, x1_2, 0, c1_kw, c1_kb, flg, x1up, 64, 16, 128, 128);

    // ---- block03: cat(x0_0 [32], x1up [64]) -> 32 -> 32 @256x256
    conv3x3_kernel<<<dim3(256, 32, 2), TB, 96 * 9 * 4, stream>>>(
        x0_0, 32, 1, x1up, 64, 0, b03_w1, b03_b1, nullptr, flg, t0a, 256, 256, 32, 1);
    conv3x3_kernel<<<dim3(256, 32, 2), TB, 32 * 9 * 4, stream>>>(
        t0a, 32, 0, nullptr, 0, 0, b03_w2, b03_b2, nullptr, flg, x0_3, 256, 256, 32, 1);

    // ---- memory-bank residual fusion (in place) + final 1x1 conv -> [2,2,256,256]
    memnorm_kernel<<<1, 64, 0, stream>>>(memw, flg, mn);
    memfuse_kernel<<<512, TB, 0, stream>>>(x0_3, mn, 256 * 256);
    final1x1_kernel<<<512, TB, 0, stream>>>(x0_3, fin_w, fin_b, flg, d_out, 256 * 256);
}

// Round 6
// 2864.395 us; speedup vs baseline: 2.6376x; 2.6376x over previous
//
#include <hip/hip_runtime.h>
#include <hip/hip_bf16.h>
#include <math.h>

typedef __hip_bfloat16 bf16;

static __device__ __forceinline__ float b2f(bf16 x) { return __bfloat162float(x); }
static __device__ __forceinline__ bf16  f2b(float x) { return __float2bfloat16(x); }

// Polymorphic input load: isb=true -> bf16 storage, else f32 storage.
static __device__ __forceinline__ float ldin(const void* p, size_t i, bool isb) {
    return isb ? b2f(((const bf16*)p)[i]) : ((const float*)p)[i];
}

// ---------------------------------------------------------------- dtype detect
__global__ void detect_kernel(const unsigned int* __restrict__ x, float* __restrict__ flagp) {
    __shared__ int sh[64];
    int insane = 0;
    for (int i = threadIdx.x; i < 1024; i += 64) {
        unsigned int lo = (x[i] & 0xFFFFu) << 16;
        float v = __uint_as_float(lo);
        if (!(fabsf(v) <= 1e6f)) insane++;
    }
    sh[threadIdx.x] = insane;
    __syncthreads();
    if (threadIdx.x == 0) {
        int t = 0;
        for (int i = 0; i < 64; ++i) t += sh[i];
        *flagp = (t < 16) ? 1.f : 0.f;            // 1 => inputs are bf16
    }
}

// ---------------------------------------------------------------- diagnostic fill
__global__ void diag_fill(unsigned int* __restrict__ out, int nwords, float val) {
    int i = blockIdx.x * blockDim.x + threadIdx.x;
    if (i < nwords) {
        unsigned short h = (unsigned short)(__float_as_uint(val) >> 16);
        out[i] = ((unsigned int)h << 16) | h;
    }
}

// ---------------------------------------------------------------- 2x2 mean pool (input -> bf16 ws)
__global__ void pool2_kernel(const void* __restrict__ in, const float* __restrict__ flg,
                             bf16* __restrict__ out, int BC, int H2, int W2) {
    bool isb = (*flg != 0.f);
    int idx = blockIdx.x * blockDim.x + threadIdx.x;
    int total = BC * H2 * W2;
    if (idx >= total) return;
    int p  = idx % (H2 * W2);
    int bc = idx / (H2 * W2);
    int h = p / W2, w = p % W2;
    int W = 2 * W2;
    size_t base = (size_t)bc * (4 * H2 * W2);
    float s = ldin(in, base + (2*h)*W + 2*w, isb)     + ldin(in, base + (2*h)*W + 2*w + 1, isb)
            + ldin(in, base + (2*h+1)*W + 2*w, isb)   + ldin(in, base + (2*h+1)*W + 2*w + 1, isb);
    out[idx] = f2b(0.25f * s);
}

// ---------------------------------------------------------------- tiled conv3x3, zero-pad SAME
// Block: 16x16 spatial tile x 16 output channels. Thread: 4 pixels x 4 cos.
// Input staged per-8-ci chunk into LDS (f32, with halo); weights per chunk.
// grid = (H/16 * W/16, Cout/16, B). modeX: 1 = external input (flag dtype),
// 0 = workspace bf16. act: 0 none, 1 relu, 2 prelu.
#define CI_CHUNK 8
__global__ __launch_bounds__(256) void conv3x3_tiled(
        const void* __restrict__ in1, int C1, int mode1,
        const void* __restrict__ in2, int C2, int mode2,
        const void* __restrict__ wt,
        const void* __restrict__ bias,
        const void* __restrict__ alpha,
        const float* __restrict__ flg,
        bf16* __restrict__ out,
        int H, int W, int Cout, int act) {
    __shared__ float in_s[CI_CHUNK][18][20];   // [ci][row+halo][col+halo(pad to 20)]
    __shared__ float w_s[16][CI_CHUNK][12];    // [co][ci][9 taps, padded to 12]

    const bool isb = (*flg != 0.f);
    const bool bi1 = mode1 ? isb : true;
    const bool bi2 = mode2 ? isb : true;
    const int Cin = C1 + C2;
    const int b = blockIdx.z;
    const int tiles_w = W >> 4;
    const int tile_r = (blockIdx.x / tiles_w) << 4;
    const int tile_c = (blockIdx.x % tiles_w) << 4;
    const int co_base = blockIdx.y << 4;

    const int tid  = threadIdx.x;
    const int cosub = tid >> 6;          // 0..3 -> 4 cos each
    const int pg    = tid & 63;          // 0..63
    const int row   = pg >> 2;           // 0..15 within tile
    const int colg  = (pg & 3) << 2;     // 0,4,8,12 (4 consecutive cols)

    float acc[4][4];
    #pragma unroll
    for (int co = 0; co < 4; ++co) {
        int cog = co_base + cosub * 4 + co;
        float bv = (cog < Cout) ? ldin(bias, cog, isb) : 0.f;
        #pragma unroll
        for (int px = 0; px < 4; ++px) acc[co][px] = bv;
    }

    for (int ci0 = 0; ci0 < Cin; ci0 += CI_CHUNK) {
        __syncthreads();
        // ---- stage input tile + halo (zero-pad at borders)
        for (int idx = tid; idx < CI_CHUNK * 18 * 18; idx += 256) {
            int ci = idx / 324, rem = idx % 324;
            int r = rem / 18, c = rem % 18;
            int gh = tile_r + r - 1, gw = tile_c + c - 1;
            float v = 0.f;
            if (gh >= 0 && gh < H && gw >= 0 && gw < W) {
                int cig = ci0 + ci;
                if (cig < C1)
                    v = ldin(in1, ((size_t)(b * C1 + cig)) * H * W + (size_t)gh * W + gw, bi1);
                else
                    v = ldin(in2, ((size_t)(b * C2 + (cig - C1))) * H * W + (size_t)gh * W + gw, bi2);
            }
            in_s[ci][r][c] = v;
        }
        // ---- stage weights for this (co_chunk, ci_chunk)
        for (int idx = tid; idx < 16 * CI_CHUNK * 9; idx += 256) {
            int co = idx / (CI_CHUNK * 9), rem = idx % (CI_CHUNK * 9);
            int ci = rem / 9, tap = rem % 9;
            int cog = co_base + co;
            w_s[co][ci][tap] = (cog < Cout)
                ? ldin(wt, ((size_t)cog * Cin + ci0 + ci) * 9 + tap, isb) : 0.f;
        }
        __syncthreads();

        for (int ci = 0; ci < CI_CHUNK; ++ci) {
            // 3 rows x 6 cols of input covering this thread's 4 pixels' taps
            float x[3][6];
            #pragma unroll
            for (int rr = 0; rr < 3; ++rr) {
                const float* rp = &in_s[ci][row + rr][colg];
                float4 v4 = *(const float4*)rp;          // 16B aligned (colg mult of 4)
                float2 v2 = *(const float2*)(rp + 4);
                x[rr][0] = v4.x; x[rr][1] = v4.y; x[rr][2] = v4.z;
                x[rr][3] = v4.w; x[rr][4] = v2.x; x[rr][5] = v2.y;
            }
            #pragma unroll
            for (int co = 0; co < 4; ++co) {
                const float* wp = &w_s[cosub * 4 + co][ci][0];
                float4 w0 = *(const float4*)wp;
                float4 w1 = *(const float4*)(wp + 4);
                float  w8 = wp[8];
                float wgt[9] = {w0.x, w0.y, w0.z, w0.w, w1.x, w1.y, w1.z, w1.w, w8};
                #pragma unroll
                for (int px = 0; px < 4; ++px) {
                    #pragma unroll
                    for (int kh = 0; kh < 3; ++kh) {
                        #pragma unroll
                        for (int kw = 0; kw < 3; ++kw)
                            acc[co][px] = fmaf(x[kh][px + kw], wgt[kh * 3 + kw], acc[co][px]);
                    }
                }
            }
        }
    }

    // ---- epilogue: activation + bf16 store
    #pragma unroll
    for (int co = 0; co < 4; ++co) {
        int cog = co_base + cosub * 4 + co;
        if (cog >= Cout) continue;
        float a = (act == 2) ? ldin(alpha, cog, isb) : 0.f;
        bf16* op = out + ((size_t)(b * Cout + cog)) * H * W
                       + (size_t)(tile_r + row) * W + tile_c + colg;
        #pragma unroll
        for (int px = 0; px < 4; ++px) {
            float v = acc[co][px];
            if (act == 1) v = fmaxf(v, 0.f);
            else if (act == 2) v = (v >= 0.f) ? v : a * v;
            op[px] = f2b(v);
        }
    }
}

// ---------------------------------------------------------------- fused CAUN tail
__global__ void caun_kernel(const bf16* __restrict__ f,
                            const void* __restrict__ xlow, int modex,
                            const void* __restrict__ kw,
                            const void* __restrict__ kb,
                            const float* __restrict__ flg,
                            bf16* __restrict__ out,
                            int C, int K, int H, int W) {
    extern __shared__ float sm[];           // 36*K weights + 36 bias
    bool isb = (*flg != 0.f);
    bool bx = modex ? isb : true;
    float* kws = sm;
    float* kbs = sm + 36 * K;
    int bc = blockIdx.y;
    int b = bc / C, c = bc % C;
    for (int i = threadIdx.x; i < 36 * K; i += blockDim.x)
        kws[i] = ldin(kw, (size_t)(c * 36) * K + i, isb);
    for (int i = threadIdx.x; i < 36; i += blockDim.x)
        kbs[i] = ldin(kb, c * 36 + i, isb);
    __syncthreads();

    int p = blockIdx.x * blockDim.x + threadIdx.x;
    if (p >= H * W) return;
    int h = p / W, w = p % W;

    float logits[36];
    #pragma unroll
    for (int j = 0; j < 36; ++j) logits[j] = kbs[j];

    const bf16* fp = f + (size_t)b * K * H * W + p;
    for (int k = 0; k < K; ++k) {
        float fv = b2f(fp[(size_t)k * H * W]);
        const float* kr = kws + k;
        #pragma unroll
        for (int j = 0; j < 36; ++j)
            logits[j] = fmaf(fv, kr[j * K], logits[j]);
    }

    float neigh[9];
    size_t xbase = (size_t)(b * C + c) * H * W;
    #pragma unroll
    for (int n = 0; n < 9; ++n) {
        int ih = h + n / 3 - 1; ih = min(max(ih, 0), H - 1);
        int iw = w + n % 3 - 1; iw = min(max(iw, 0), W - 1);
        neigh[n] = ldin(xlow, xbase + (size_t)ih * W + iw, bx);
    }

    bf16* op = out + (size_t)(b * C + c) * 4 * H * W;
    #pragma unroll
    for (int u = 0; u < 2; ++u) {
        #pragma unroll
        for (int v = 0; v < 2; ++v) {
            int g = u * 2 + v;
            float mx = -1e30f;
            #pragma unroll
            for (int n = 0; n < 9; ++n) mx = fmaxf(mx, logits[n * 4 + g]);
            float se = 0.f, acc = 0.f;
            #pragma unroll
            for (int n = 0; n < 9; ++n) {
                float e = expf(logits[n * 4 + g] - mx);
                se += e;
                acc = fmaf(e, neigh[n], acc);
            }
            int L = ((w * 2 + v) * H + h) * 2 + u;   // torch permute(0,1,5,3,4,2)
            op[L] = f2b(acc / se);
        }
    }
}

// ---------------------------------------------------------------- memory bank: row-l2norm of mem
__global__ void memnorm_kernel(const void* __restrict__ mem, const float* __restrict__ flg,
                               float* __restrict__ mn) {
    bool isb = (*flg != 0.f);
    int s = threadIdx.x;          // 64 slots
    float v[32];
    float ss = 0.f;
    #pragma unroll
    for (int c = 0; c < 32; ++c) { v[c] = ldin(mem, s * 32 + c, isb); ss += v[c] * v[c]; }
    float inv = 1.f / fmaxf(sqrtf(ss), 1e-12f);
    #pragma unroll
    for (int c = 0; c < 32; ++c) mn[s * 32 + c] = v[c] * inv;
}

// ---------------------------------------------------------------- memory fusion (in place, bf16 ws)
__global__ void memfuse_kernel(bf16* __restrict__ x, const float* __restrict__ mn, int HW) {
    __shared__ float mns[64 * 32];
    for (int i = threadIdx.x; i < 64 * 32; i += blockDim.x) mns[i] = mn[i];
    __syncthreads();
    int idx = blockIdx.x * blockDim.x + threadIdx.x;   // over B*HW
    int b = idx / HW, p = idx % HW;
    bf16* xp = x + (size_t)b * 32 * HW + p;

    float feat[32];
    float ss = 0.f;
    #pragma unroll
    for (int c = 0; c < 32; ++c) { feat[c] = b2f(xp[(size_t)c * HW]); ss += feat[c] * feat[c]; }
    float inv = 1.f / fmaxf(sqrtf(ss), 1e-12f);

    float d[64];
    float mx = -1e30f;
    for (int s = 0; s < 64; ++s) {
        float acc = 0.f;
        const float* mr = mns + s * 32;
        #pragma unroll
        for (int c = 0; c < 32; ++c) acc = fmaf(feat[c] * inv, mr[c], acc);
        d[s] = acc;
        mx = fmaxf(mx, acc);
    }
    float se = 0.f;
    for (int s = 0; s < 64; ++s) { d[s] = expf(d[s] - mx); se += d[s]; }
    float rse = 1.f / se;
    #pragma unroll
    for (int c = 0; c < 32; ++c) {
        float acc = 0.f;
        for (int s = 0; s < 64; ++s) acc = fmaf(d[s], mns[s * 32 + c], acc);
        xp[(size_t)c * HW] = f2b(feat[c] + acc * rse);
    }
}

// ---------------------------------------------------------------- final 1x1 conv 32 -> 2
__global__ void final1x1_kernel(const bf16* __restrict__ x,
                                const void* __restrict__ fw, const void* __restrict__ fb,
                                const float* __restrict__ flg,
                                void* __restrict__ out, int HW) {
    bool isb = (*flg != 0.f);
    int idx = blockIdx.x * blockDim.x + threadIdx.x;   // over B*HW
    int b = idx / HW, p = idx % HW;
    const bf16* xp = x + (size_t)b * 32 * HW + p;
    float a0 = ldin(fb, 0, isb), a1 = ldin(fb, 1, isb);
    #pragma unroll
    for (int c = 0; c < 32; ++c) {
        float v = b2f(xp[(size_t)c * HW]);
        a0 = fmaf(v, ldin(fw, c, isb), a0);
        a1 = fmaf(v, ldin(fw, 32 + c, isb), a1);
    }
    size_t i0 = (size_t)b * 2 * HW + p;
    size_t i1 = i0 + HW;
    if (isb) { ((bf16*)out)[i0] = f2b(a0); ((bf16*)out)[i1] = f2b(a1); }
    else     { ((float*)out)[i0] = a0;     ((float*)out)[i1] = a1; }
}

// ================================================================ host
extern "C" void kernel_launch(void* const* d_in, const int* in_sizes, int n_in,
                              void* d_out, int out_size, void* d_ws, size_t ws_size,
                              hipStream_t stream) {
    const void* x0_0 = d_in[0];
    const void* x1_0 = d_in[1];
    const void* x2_0 = d_in[2];
    const void* x3_0 = d_in[3];
    const void* c3_w1 = d_in[4];  const void* c3_b1 = d_in[5];  const void* c3_a1 = d_in[6];
    const void* c3_w2 = d_in[7];  const void* c3_b2 = d_in[8];  const void* c3_a2 = d_in[9];
    const void* c3_kw = d_in[10]; const void* c3_kb = d_in[11];
    const void* c2_w1 = d_in[12]; const void* c2_b1 = d_in[13]; const void* c2_a1 = d_in[14];
    const void* c2_w2 = d_in[15]; const void* c2_b2 = d_in[16]; const void* c2_a2 = d_in[17];
    const void* c2_kw = d_in[18]; const void* c2_kb = d_in[19];
    const void* c1_w1 = d_in[20]; const void* c1_b1 = d_in[21]; const void* c1_a1 = d_in[22];
    const void* c1_w2 = d_in[23]; const void* c1_b2 = d_in[24]; const void* c1_a2 = d_in[25];
    const void* c1_kw = d_in[26]; const void* c1_kb = d_in[27];
    const void* b21_w1 = d_in[28]; const void* b21_b1 = d_in[29];
    const void* b21_w2 = d_in[30]; const void* b21_b2 = d_in[31];
    const void* b12_w1 = d_in[32]; const void* b12_b1 = d_in[33];
    const void* b12_w2 = d_in[34]; const void* b12_b2 = d_in[35];
    const void* b03_w1 = d_in[36]; const void* b03_b1 = d_in[37];
    const void* b03_w2 = d_in[38]; const void* b03_b2 = d_in[39];
    const void* fin_w = d_in[40];  const void* fin_b = d_in[41];
    const void* memw  = d_in[42];
    (void)in_sizes; (void)n_in;

    const int TB = 256;
    auto blocks = [](int n) { return (n + 255) / 256; };

    const size_t NEED = 25165824 + 65536;
    if (ws_size < NEED) {
        diag_fill<<<blocks(out_size / 2), TB, 0, stream>>>(
            (unsigned int*)d_out, out_size / 2, (float)ws_size);
        return;
    }
    size_t tail = (ws_size - 65536) & ~(size_t)255;
    float* mn  = (float*)((char*)d_ws + tail);          // 8 KB
    float* flg = (float*)((char*)d_ws + tail + 8192);   // 4 B

    // 24 MiB arena, hand-verified live-range plan (offsets in bf16 elements):
    bf16* A = (bf16*)d_ws;
    bf16* x3up  = A + 0;
    bf16* ctx3p = A + 2097152;
    bf16* f3a   = A + 2359296;
    bf16* f3b   = A + 2621440;
    bf16* t2a   = A + 2097152;
    bf16* x2_1  = A + 0;
    bf16* ctx2  = A + 1048576;
    bf16* f2a   = A + 1572864;
    bf16* f2b   = A + 2097152;
    bf16* x2up  = A + 2359296;
    bf16* t1a   = A + 0;
    bf16* x1_2  = A + 10485760;
    bf16* ctx1  = A + 4194304;
    bf16* f1a   = A + 5242880;
    bf16* f1b   = A + 9437184;
    bf16* x1up  = A + 0;
    bf16* t0a   = A + 8388608;
    bf16* x0_3  = A + 0;

    // ---- dtype detection (writes flg)
    detect_kernel<<<1, 64, 0, stream>>>((const unsigned int*)x0_0, flg);

    // conv grid helper: (H/16 * W/16, Cout/16, 2)
    auto cgrid = [](int H, int W, int Cout) { return dim3((H >> 4) * (W >> 4), Cout >> 4, 2); };

    // ---- caun3: x3_0 [2,256,32,32], ctx = pool(x2_0) -> [2,128,32,32]
    pool2_kernel<<<blocks(262144), TB, 0, stream>>>(x2_0, flg, ctx3p, 256, 32, 32);
    conv3x3_tiled<<<cgrid(32, 32, 128), TB, 0, stream>>>(
        ctx3p, 128, 0, nullptr, 0, 0, c3_w1, c3_b1, c3_a1, flg, f3a, 32, 32, 128, 2);
    conv3x3_tiled<<<cgrid(32, 32, 64), TB, 0, stream>>>(
        f3a, 128, 0, nullptr, 0, 0, c3_w2, c3_b2, c3_a2, flg, f3b, 32, 32, 64, 2);
    caun_kernel<<<dim3(4, 512), TB, (36 * 64 + 36) * 4, stream>>>(
        f3b, x3_0, 1, c3_kw, c3_kb, flg, x3up, 256, 64, 32, 32);

    // ---- block21: cat(x2_0 [128], x3up [256]) -> 128 -> 128 @64x64
    conv3x3_tiled<<<cgrid(64, 64, 128), TB, 0, stream>>>(
        x2_0, 128, 1, x3up, 256, 0, b21_w1, b21_b1, nullptr, flg, t2a, 64, 64, 128, 1);
    conv3x3_tiled<<<cgrid(64, 64, 128), TB, 0, stream>>>(
        t2a, 128, 0, nullptr, 0, 0, b21_w2, b21_b2, nullptr, flg, x2_1, 64, 64, 128, 1);

    // ---- caun2: x2_1 [2,128,64,64], ctx = pool(x1_0) -> [2,64,64,64]
    pool2_kernel<<<blocks(524288), TB, 0, stream>>>(x1_0, flg, ctx2, 128, 64, 64);
    conv3x3_tiled<<<cgrid(64, 64, 64), TB, 0, stream>>>(
        ctx2, 64, 0, nullptr, 0, 0, c2_w1, c2_b1, c2_a1, flg, f2a, 64, 64, 64, 2);
    conv3x3_tiled<<<cgrid(64, 64, 32), TB, 0, stream>>>(
        f2a, 64, 0, nullptr, 0, 0, c2_w2, c2_b2, c2_a2, flg, f2b, 64, 64, 32, 2);
    caun_kernel<<<dim3(16, 256), TB, (36 * 32 + 36) * 4, stream>>>(
        f2b, x2_1, 0, c2_kw, c2_kb, flg, x2up, 128, 32, 64, 64);

    // ---- block12: cat(x1_0 [64], x2up [128]) -> 64 -> 64 @128x128
    conv3x3_tiled<<<cgrid(128, 128, 64), TB, 0, stream>>>(
        x1_0, 64, 1, x2up, 128, 0, b12_w1, b12_b1, nullptr, flg, t1a, 128, 128, 64, 1);
    conv3x3_tiled<<<cgrid(128, 128, 64), TB, 0, stream>>>(
        t1a, 64, 0, nullptr, 0, 0, b12_w2, b12_b2, nullptr, flg, x1_2, 128, 128, 64, 1);

    // ---- caun1: x1_2 [2,64,128,128], ctx = pool(x0_0) -> [2,32,128,128]
    pool2_kernel<<<blocks(1048576), TB, 0, stream>>>(x0_0, flg, ctx1, 64, 128, 128);
    conv3x3_tiled<<<cgrid(128, 128, 32), TB, 0, stream>>>(
        ctx1, 32, 0, nullptr, 0, 0, c1_w1, c1_b1, c1_a1, flg, f1a, 128, 128, 32, 2);
    conv3x3_tiled<<<cgrid(128, 128, 16), TB, 0, stream>>>(
        f1a, 32, 0, nullptr, 0, 0, c1_w2, c1_b2, c1_a2, flg, f1b, 128, 128, 16, 2);
    caun_kernel<<<dim3(64, 128), TB, (36 * 16 + 36) * 4, stream>>>(
        f1b, x1_2, 0, c1_kw, c1_kb, flg, x1up, 64, 16, 128, 128);

    // ---- block03: cat(x0_0 [32], x1up [64]) -> 32 -> 32 @256x256
    conv3x3_tiled<<<cgrid(256, 256, 32), TB, 0, stream>>>(
        x0_0, 32, 1, x1up, 64, 0, b03_w1, b03_b1, nullptr, flg, t0a, 256, 256, 32, 1);
    conv3x3_tiled<<<cgrid(256, 256, 32), TB, 0, stream>>>(
        t0a, 32, 0, nullptr, 0, 0, b03_w2, b03_b2, nullptr, flg, x0_3, 256, 256, 32, 1);

    // ---- memory-bank residual fusion (in place) + final 1x1 conv -> [2,2,256,256]
    memnorm_kernel<<<1, 64, 0, stream>>>(memw, flg, mn);
    memfuse_kernel<<<512, TB, 0, stream>>>(x0_3, mn, 256 * 256);
    final1x1_kernel<<<512, TB, 0, stream>>>(x0_3, fin_w, fin_b, flg, d_out, 256 * 256);
}

// Round 7
// 1906.467 us; speedup vs baseline: 3.9629x; 1.5025x over previous
//
#include <hip/hip_runtime.h>
#include <hip/hip_bf16.h>
#include <math.h>

typedef __hip_bfloat16 bf16;

static __device__ __forceinline__ float b2f(bf16 x) { return __bfloat162float(x); }
static __device__ __forceinline__ bf16  f2b(float x) { return __float2bfloat16(x); }

// Polymorphic input load: isb=true -> bf16 storage, else f32 storage.
static __device__ __forceinline__ float ldin(const void* p, size_t i, bool isb) {
    return isb ? b2f(((const bf16*)p)[i]) : ((const float*)p)[i];
}

// ---------------------------------------------------------------- dtype detect
__global__ void detect_kernel(const unsigned int* __restrict__ x, float* __restrict__ flagp) {
    __shared__ int sh[64];
    int insane = 0;
    for (int i = threadIdx.x; i < 1024; i += 64) {
        unsigned int lo = (x[i] & 0xFFFFu) << 16;
        float v = __uint_as_float(lo);
        if (!(fabsf(v) <= 1e6f)) insane++;
    }
    sh[threadIdx.x] = insane;
    __syncthreads();
    if (threadIdx.x == 0) {
        int t = 0;
        for (int i = 0; i < 64; ++i) t += sh[i];
        *flagp = (t < 16) ? 1.f : 0.f;            // 1 => inputs are bf16
    }
}

// ---------------------------------------------------------------- diagnostic fill
__global__ void diag_fill(unsigned int* __restrict__ out, int nwords, float val) {
    int i = blockIdx.x * blockDim.x + threadIdx.x;
    if (i < nwords) {
        unsigned short h = (unsigned short)(__float_as_uint(val) >> 16);
        out[i] = ((unsigned int)h << 16) | h;
    }
}

// ---------------------------------------------------------------- 2x2 mean pool (input -> bf16 ws)
__global__ void pool2_kernel(const void* __restrict__ in, const float* __restrict__ flg,
                             bf16* __restrict__ out, int BC, int H2, int W2) {
    bool isb = (*flg != 0.f);
    int idx = blockIdx.x * blockDim.x + threadIdx.x;
    int total = BC * H2 * W2;
    if (idx >= total) return;
    int p  = idx % (H2 * W2);
    int bc = idx / (H2 * W2);
    int h = p / W2, w = p % W2;
    int W = 2 * W2;
    size_t base = (size_t)bc * (4 * H2 * W2);
    float s = ldin(in, base + (2*h)*W + 2*w, isb)     + ldin(in, base + (2*h)*W + 2*w + 1, isb)
            + ldin(in, base + (2*h+1)*W + 2*w, isb)   + ldin(in, base + (2*h+1)*W + 2*w + 1, isb);
    out[idx] = f2b(0.25f * s);
}

// ---------------------------------------------------------------- tiled conv3x3, zero-pad SAME
// Block: 16x16 spatial tile x 8 output channels, 256 threads (4 waves).
// Wave w covers rows 4w..4w+3. Lane: co = lane&7, colg = ((lane>>3)&3)*4,
// rpair = lane>>5 -> out rows R0=4w+2*rpair, R0+1. Each thread: 2 rows x 4 px x 1 co.
// LDS input reads: 8 distinct addresses x 8-lane broadcast -> conflict-free.
// grid = (H/16 * W/16, Cout/8, B). modeX: 1 = external input (flag dtype), 0 = ws bf16.
// act: 0 none, 1 relu, 2 prelu.
#define CI_CHUNK 8
__global__ __launch_bounds__(256, 4) void conv3x3_tiled(
        const void* __restrict__ in1, int C1, int mode1,
        const void* __restrict__ in2, int C2, int mode2,
        const void* __restrict__ wt,
        const void* __restrict__ bias,
        const void* __restrict__ alpha,
        const float* __restrict__ flg,
        bf16* __restrict__ out,
        int H, int W, int Cout, int act) {
    __shared__ float in_s[CI_CHUNK][18][20];   // [ci][row+halo][col+halo pad 20] (80B rows, 16B-aligned)
    __shared__ float w_s[CI_CHUNK][8][12];     // [ci][co][9 taps pad 12] -> co starts on distinct banks

    const bool isb = (*flg != 0.f);
    const bool bi1 = mode1 ? isb : true;
    const bool bi2 = mode2 ? isb : true;
    const int Cin = C1 + C2;
    const int b = blockIdx.z;
    const int tiles_w = W >> 4;
    const int tile_r = (blockIdx.x / tiles_w) << 4;
    const int tile_c = (blockIdx.x % tiles_w) << 4;
    const int co_base = blockIdx.y << 3;

    const int tid   = threadIdx.x;
    const int wave  = tid >> 6;
    const int lane  = tid & 63;
    const int col   = lane & 7;                 // local co
    const int colg  = ((lane >> 3) & 3) << 2;   // 0,4,8,12
    const int rpair = (lane >> 5) & 1;
    const int R0    = (wave << 2) + (rpair << 1);   // first of 2 output rows

    const int cog = co_base + col;
    float bv = ldin(bias, cog, isb);
    float acc[2][4];
    #pragma unroll
    for (int r2 = 0; r2 < 2; ++r2)
        #pragma unroll
        for (int px = 0; px < 4; ++px) acc[r2][px] = bv;

    for (int ci0 = 0; ci0 < Cin; ci0 += CI_CHUNK) {
        __syncthreads();
        // ---- stage input tile + halo (zero-pad at borders)
        for (int idx = tid; idx < CI_CHUNK * 18 * 18; idx += 256) {
            int ci = idx / 324, rem = idx % 324;
            int r = rem / 18, c = rem % 18;
            int gh = tile_r + r - 1, gw = tile_c + c - 1;
            float v = 0.f;
            if (gh >= 0 && gh < H && gw >= 0 && gw < W) {
                int cig = ci0 + ci;
                if (cig < C1)
                    v = ldin(in1, ((size_t)(b * C1 + cig)) * H * W + (size_t)gh * W + gw, bi1);
                else
                    v = ldin(in2, ((size_t)(b * C2 + (cig - C1))) * H * W + (size_t)gh * W + gw, bi2);
            }
            in_s[ci][r][c] = v;
        }
        // ---- stage weights for this (co_chunk=8, ci_chunk)
        for (int idx = tid; idx < CI_CHUNK * 8 * 9; idx += 256) {
            int ci = idx / 72, rem = idx % 72;
            int co = rem / 9, tap = rem % 9;
            w_s[ci][co][tap] = ldin(wt, ((size_t)(co_base + co) * Cin + ci0 + ci) * 9 + tap, isb);
        }
        __syncthreads();

        #pragma unroll
        for (int ci = 0; ci < CI_CHUNK; ++ci) {
            // 4 input rows x 6 cols covering this thread's 2x4 output pixels
            float xv[4][6];
            #pragma unroll
            for (int rr = 0; rr < 4; ++rr) {
                const float* rp = &in_s[ci][R0 + rr][colg];
                float4 v4 = *(const float4*)rp;
                float2 v2 = *(const float2*)(rp + 4);
                xv[rr][0] = v4.x; xv[rr][1] = v4.y; xv[rr][2] = v4.z;
                xv[rr][3] = v4.w; xv[rr][4] = v2.x; xv[rr][5] = v2.y;
            }
            const float* wp = &w_s[ci][col][0];
            float4 w0 = *(const float4*)wp;
            float4 w1 = *(const float4*)(wp + 4);
            float  w8 = wp[8];
            float wgt[9] = {w0.x, w0.y, w0.z, w0.w, w1.x, w1.y, w1.z, w1.w, w8};
            #pragma unroll
            for (int r2 = 0; r2 < 2; ++r2)
                #pragma unroll
                for (int kh = 0; kh < 3; ++kh)
                    #pragma unroll
                    for (int kw = 0; kw < 3; ++kw)
                        #pragma unroll
                        for (int px = 0; px < 4; ++px)
                            acc[r2][px] = fmaf(xv[r2 + kh][px + kw], wgt[kh * 3 + kw], acc[r2][px]);
        }
    }

    // ---- epilogue: activation + bf16 store (2 rows x 4 px)
    float a = (act == 2) ? ldin(alpha, cog, isb) : 0.f;
    #pragma unroll
    for (int r2 = 0; r2 < 2; ++r2) {
        bf16* op = out + ((size_t)(b * Cout + cog)) * H * W
                       + (size_t)(tile_r + R0 + r2) * W + tile_c + colg;
        #pragma unroll
        for (int px = 0; px < 4; ++px) {
            float v = acc[r2][px];
            if (act == 1) v = fmaxf(v, 0.f);
            else if (act == 2) v = (v >= 0.f) ? v : a * v;
            op[px] = f2b(v);
        }
    }
}

// ---------------------------------------------------------------- fused CAUN tail
__global__ void caun_kernel(const bf16* __restrict__ f,
                            const void* __restrict__ xlow, int modex,
                            const void* __restrict__ kw,
                            const void* __restrict__ kb,
                            const float* __restrict__ flg,
                            bf16* __restrict__ out,
                            int C, int K, int H, int W) {
    extern __shared__ float sm[];           // 36*K weights + 36 bias
    bool isb = (*flg != 0.f);
    bool bx = modex ? isb : true;
    float* kws = sm;
    float* kbs = sm + 36 * K;
    int bc = blockIdx.y;
    int b = bc / C, c = bc % C;
    for (int i = threadIdx.x; i < 36 * K; i += blockDim.x)
        kws[i] = ldin(kw, (size_t)(c * 36) * K + i, isb);
    for (int i = threadIdx.x; i < 36; i += blockDim.x)
        kbs[i] = ldin(kb, c * 36 + i, isb);
    __syncthreads();

    int p = blockIdx.x * blockDim.x + threadIdx.x;
    if (p >= H * W) return;
    int h = p / W, w = p % W;

    float logits[36];
    #pragma unroll
    for (int j = 0; j < 36; ++j) logits[j] = kbs[j];

    const bf16* fp = f + (size_t)b * K * H * W + p;
    for (int k = 0; k < K; ++k) {
        float fv = b2f(fp[(size_t)k * H * W]);
        const float* kr = kws + k;
        #pragma unroll
        for (int j = 0; j < 36; ++j)
            logits[j] = fmaf(fv, kr[j * K], logits[j]);
    }

    float neigh[9];
    size_t xbase = (size_t)(b * C + c) * H * W;
    #pragma unroll
    for (int n = 0; n < 9; ++n) {
        int ih = h + n / 3 - 1; ih = min(max(ih, 0), H - 1);
        int iw = w + n % 3 - 1; iw = min(max(iw, 0), W - 1);
        neigh[n] = ldin(xlow, xbase + (size_t)ih * W + iw, bx);
    }

    bf16* op = out + (size_t)(b * C + c) * 4 * H * W;
    #pragma unroll
    for (int u = 0; u < 2; ++u) {
        #pragma unroll
        for (int v = 0; v < 2; ++v) {
            int g = u * 2 + v;
            float mx = -1e30f;
            #pragma unroll
            for (int n = 0; n < 9; ++n) mx = fmaxf(mx, logits[n * 4 + g]);
            float se = 0.f, acc = 0.f;
            #pragma unroll
            for (int n = 0; n < 9; ++n) {
                float e = expf(logits[n * 4 + g] - mx);
                se += e;
                acc = fmaf(e, neigh[n], acc);
            }
            int L = ((w * 2 + v) * H + h) * 2 + u;   // torch permute(0,1,5,3,4,2)
            op[L] = f2b(acc / se);
        }
    }
}

// ---------------------------------------------------------------- memory bank: row-l2norm of mem
__global__ void memnorm_kernel(const void* __restrict__ mem, const float* __restrict__ flg,
                               float* __restrict__ mn) {
    bool isb = (*flg != 0.f);
    int s = threadIdx.x;          // 64 slots
    float v[32];
    float ss = 0.f;
    #pragma unroll
    for (int c = 0; c < 32; ++c) { v[c] = ldin(mem, s * 32 + c, isb); ss += v[c] * v[c]; }
    float inv = 1.f / fmaxf(sqrtf(ss), 1e-12f);
    #pragma unroll
    for (int c = 0; c < 32; ++c) mn[s * 32 + c] = v[c] * inv;
}

// ---------------------------------------------------------------- memory fusion (in place, bf16 ws)
// Online accumulation: dots of two unit vectors are in [-1,1], so exp() is safe
// without max subtraction (softmax is shift-invariant). No d[64] -> no spills.
__global__ __launch_bounds__(256, 2) void memfuse_kernel(
        bf16* __restrict__ x, const float* __restrict__ mn, int HW) {
    __shared__ float mns[64 * 32];
    for (int i = threadIdx.x; i < 64 * 32; i += blockDim.x) mns[i] = mn[i];
    __syncthreads();
    int idx = blockIdx.x * blockDim.x + threadIdx.x;   // over B*HW
    int b = idx / HW, p = idx % HW;
    bf16* xp = x + (size_t)b * 32 * HW + p;

    float feat[32];
    float ss = 0.f;
    #pragma unroll
    for (int c = 0; c < 32; ++c) { feat[c] = b2f(xp[(size_t)c * HW]); ss += feat[c] * feat[c]; }
    float inv = 1.f / fmaxf(sqrtf(ss), 1e-12f);

    float se = 0.f;
    float racc[32];
    #pragma unroll
    for (int c = 0; c < 32; ++c) racc[c] = 0.f;

    for (int s = 0; s < 64; ++s) {
        const float* mr = mns + s * 32;
        float dot = 0.f;
        #pragma unroll
        for (int c = 0; c < 32; ++c) dot = fmaf(feat[c], mr[c], dot);
        float e = expf(dot * inv);
        se += e;
        #pragma unroll
        for (int c = 0; c < 32; ++c) racc[c] = fmaf(e, mr[c], racc[c]);
    }
    float rse = 1.f / se;
    #pragma unroll
    for (int c = 0; c < 32; ++c)
        xp[(size_t)c * HW] = f2b(feat[c] + racc[c] * rse);
}

// ---------------------------------------------------------------- final 1x1 conv 32 -> 2
__global__ void final1x1_kernel(const bf16* __restrict__ x,
                                const void* __restrict__ fw, const void* __restrict__ fb,
                                const float* __restrict__ flg,
                                void* __restrict__ out, int HW) {
    bool isb = (*flg != 0.f);
    int idx = blockIdx.x * blockDim.x + threadIdx.x;   // over B*HW
    int b = idx / HW, p = idx % HW;
    const bf16* xp = x + (size_t)b * 32 * HW + p;
    float a0 = ldin(fb, 0, isb), a1 = ldin(fb, 1, isb);
    #pragma unroll
    for (int c = 0; c < 32; ++c) {
        float v = b2f(xp[(size_t)c * HW]);
        a0 = fmaf(v, ldin(fw, c, isb), a0);
        a1 = fmaf(v, ldin(fw, 32 + c, isb), a1);
    }
    size_t i0 = (size_t)b * 2 * HW + p;
    size_t i1 = i0 + HW;
    if (isb) { ((bf16*)out)[i0] = f2b(a0); ((bf16*)out)[i1] = f2b(a1); }
    else     { ((float*)out)[i0] = a0;     ((float*)out)[i1] = a1; }
}

// ================================================================ host
extern "C" void kernel_launch(void* const* d_in, const int* in_sizes, int n_in,
                              void* d_out, int out_size, void* d_ws, size_t ws_size,
                              hipStream_t stream) {
    const void* x0_0 = d_in[0];
    const void* x1_0 = d_in[1];
    const void* x2_0 = d_in[2];
    const void* x3_0 = d_in[3];
    const void* c3_w1 = d_in[4];  const void* c3_b1 = d_in[5];  const void* c3_a1 = d_in[6];
    const void* c3_w2 = d_in[7];  const void* c3_b2 = d_in[8];  const void* c3_a2 = d_in[9];
    const void* c3_kw = d_in[10]; const void* c3_kb = d_in[11];
    const void* c2_w1 = d_in[12]; const void* c2_b1 = d_in[13]; const void* c2_a1 = d_in[14];
    const void* c2_w2 = d_in[15]; const void* c2_b2 = d_in[16]; const void* c2_a2 = d_in[17];
    const void* c2_kw = d_in[18]; const void* c2_kb = d_in[19];
    const void* c1_w1 = d_in[20]; const void* c1_b1 = d_in[21]; const void* c1_a1 = d_in[22];
    const void* c1_w2 = d_in[23]; const void* c1_b2 = d_in[24]; const void* c1_a2 = d_in[25];
    const void* c1_kw = d_in[26]; const void* c1_kb = d_in[27];
    const void* b21_w1 = d_in[28]; const void* b21_b1 = d_in[29];
    const void* b21_w2 = d_in[30]; const void* b21_b2 = d_in[31];
    const void* b12_w1 = d_in[32]; const void* b12_b1 = d_in[33];
    const void* b12_w2 = d_in[34]; const void* b12_b2 = d_in[35];
    const void* b03_w1 = d_in[36]; const void* b03_b1 = d_in[37];
    const void* b03_w2 = d_in[38]; const void* b03_b2 = d_in[39];
    const void* fin_w = d_in[40];  const void* fin_b = d_in[41];
    const void* memw  = d_in[42];
    (void)in_sizes; (void)n_in;

    const int TB = 256;
    auto blocks = [](int n) { return (n + 255) / 256; };

    const size_t NEED = 25165824 + 65536;
    if (ws_size < NEED) {
        diag_fill<<<blocks(out_size / 2), TB, 0, stream>>>(
            (unsigned int*)d_out, out_size / 2, (float)ws_size);
        return;
    }
    size_t tail = (ws_size - 65536) & ~(size_t)255;
    float* mn  = (float*)((char*)d_ws + tail);          // 8 KB
    float* flg = (float*)((char*)d_ws + tail + 8192);   // 4 B

    // 24 MiB arena, hand-verified live-range plan (offsets in bf16 elements):
    bf16* A = (bf16*)d_ws;
    bf16* x3up  = A + 0;
    bf16* ctx3p = A + 2097152;
    bf16* f3a   = A + 2359296;
    bf16* f3b   = A + 2621440;
    bf16* t2a   = A + 2097152;
    bf16* x2_1  = A + 0;
    bf16* ctx2  = A + 1048576;
    bf16* f2a   = A + 1572864;
    bf16* f2b   = A + 2097152;
    bf16* x2up  = A + 2359296;
    bf16* t1a   = A + 0;
    bf16* x1_2  = A + 10485760;
    bf16* ctx1  = A + 4194304;
    bf16* f1a   = A + 5242880;
    bf16* f1b   = A + 9437184;
    bf16* x1up  = A + 0;
    bf16* t0a   = A + 8388608;
    bf16* x0_3  = A + 0;

    // ---- dtype detection (writes flg)
    detect_kernel<<<1, 64, 0, stream>>>((const unsigned int*)x0_0, flg);

    // conv grid helper: (H/16 * W/16, Cout/8, 2)
    auto cgrid = [](int H, int W, int Cout) { return dim3((H >> 4) * (W >> 4), Cout >> 3, 2); };

    // ---- caun3: x3_0 [2,256,32,32], ctx = pool(x2_0) -> [2,128,32,32]
    pool2_kernel<<<blocks(262144), TB, 0, stream>>>(x2_0, flg, ctx3p, 256, 32, 32);
    conv3x3_tiled<<<cgrid(32, 32, 128), TB, 0, stream>>>(
        ctx3p, 128, 0, nullptr, 0, 0, c3_w1, c3_b1, c3_a1, flg, f3a, 32, 32, 128, 2);
    conv3x3_tiled<<<cgrid(32, 32, 64), TB, 0, stream>>>(
        f3a, 128, 0, nullptr, 0, 0, c3_w2, c3_b2, c3_a2, flg, f3b, 32, 32, 64, 2);
    caun_kernel<<<dim3(4, 512), TB, (36 * 64 + 36) * 4, stream>>>(
        f3b, x3_0, 1, c3_kw, c3_kb, flg, x3up, 256, 64, 32, 32);

    // ---- block21: cat(x2_0 [128], x3up [256]) -> 128 -> 128 @64x64
    conv3x3_tiled<<<cgrid(64, 64, 128), TB, 0, stream>>>(
        x2_0, 128, 1, x3up, 256, 0, b21_w1, b21_b1, nullptr, flg, t2a, 64, 64, 128, 1);
    conv3x3_tiled<<<cgrid(64, 64, 128), TB, 0, stream>>>(
        t2a, 128, 0, nullptr, 0, 0, b21_w2, b21_b2, nullptr, flg, x2_1, 64, 64, 128, 1);

    // ---- caun2: x2_1 [2,128,64,64], ctx = pool(x1_0) -> [2,64,64,64]
    pool2_kernel<<<blocks(524288), TB, 0, stream>>>(x1_0, flg, ctx2, 128, 64, 64);
    conv3x3_tiled<<<cgrid(64, 64, 64), TB, 0, stream>>>(
        ctx2, 64, 0, nullptr, 0, 0, c2_w1, c2_b1, c2_a1, flg, f2a, 64, 64, 64, 2);
    conv3x3_tiled<<<cgrid(64, 64, 32), TB, 0, stream>>>(
        f2a, 64, 0, nullptr, 0, 0, c2_w2, c2_b2, c2_a2, flg, f2b, 64, 64, 32, 2);
    caun_kernel<<<dim3(16, 256), TB, (36 * 32 + 36) * 4, stream>>>(
        f2b, x2_1, 0, c2_kw, c2_kb, flg, x2up, 128, 32, 64, 64);

    // ---- block12: cat(x1_0 [64], x2up [128]) -> 64 -> 64 @128x128
    conv3x3_tiled<<<cgrid(128, 128, 64), TB, 0, stream>>>(
        x1_0, 64, 1, x2up, 128, 0, b12_w1, b12_b1, nullptr, flg, t1a, 128, 128, 64, 1);
    conv3x3_tiled<<<cgrid(128, 128, 64), TB, 0, stream>>>(
        t1a, 64, 0, nullptr, 0, 0, b12_w2, b12_b2, nullptr, flg, x1_2, 128, 128, 64, 1);

    // ---- caun1: x1_2 [2,64,128,128], ctx = pool(x0_0) -> [2,32,128,128]
    pool2_kernel<<<blocks(1048576), TB, 0, stream>>>(x0_0, flg, ctx1, 64, 128, 128);
    conv3x3_tiled<<<cgrid(128, 128, 32), TB, 0, stream>>>(
        ctx1, 32, 0, nullptr, 0, 0, c1_w1, c1_b1, c1_a1, flg, f1a, 128, 128, 32, 2);
    conv3x3_tiled<<<cgrid(128, 128, 16), TB, 0, stream>>>(
        f1a, 32, 0, nullptr, 0, 0, c1_w2, c1_b2, c1_a2, flg, f1b, 128, 128, 16, 2);
    caun_kernel<<<dim3(64, 128), TB, (36 * 16 + 36) * 4, stream>>>(
        f1b, x1_2, 0, c1_kw, c1_kb, flg, x1up, 64, 16, 128, 128);

    // ---- block03: cat(x0_0 [32], x1up [64]) -> 32 -> 32 @256x256
    conv3x3_tiled<<<cgrid(256, 256, 32), TB, 0, stream>>>(
        x0_0, 32, 1, x1up, 64, 0, b03_w1, b03_b1, nullptr, flg, t0a, 256, 256, 32, 1);
    conv3x3_tiled<<<cgrid(256, 256, 32), TB, 0, stream>>>(
        t0a, 32, 0, nullptr, 0, 0, b03_w2, b03_b2, nullptr, flg, x0_3, 256, 256, 32, 1);

    // ---- memory-bank residual fusion (in place) + final 1x1 conv -> [2,2,256,256]
    memnorm_kernel<<<1, 64, 0, stream>>>(memw, flg, mn);
    memfuse_kernel<<<512, TB, 0, stream>>>(x0_3, mn, 256 * 256);
    final1x1_kernel<<<512, TB, 0, stream>>>(x0_3, fin_w, fin_b, flg, d_out, 256 * 256);
}

// Round 8
// 1453.284 us; speedup vs baseline: 5.1986x; 1.3118x over previous
//
#include <hip/hip_runtime.h>
#include <hip/hip_bf16.h>
#include <math.h>

typedef __hip_bfloat16 bf16;
typedef short short8 __attribute__((ext_vector_type(8)));   // bf16x8 MFMA frag (4 VGPRs)
typedef float f32x4 __attribute__((ext_vector_type(4)));    // MFMA accumulator

static __device__ __forceinline__ float b2f(bf16 x) { return __bfloat162float(x); }
static __device__ __forceinline__ bf16  f2b(float x) { return __float2bfloat16(x); }

// Polymorphic input load: isb=true -> bf16 storage, else f32 storage.
static __device__ __forceinline__ float ldin(const void* p, size_t i, bool isb) {
    return isb ? b2f(((const bf16*)p)[i]) : ((const float*)p)[i];
}

// ---------------------------------------------------------------- dtype detect
__global__ void detect_kernel(const unsigned int* __restrict__ x, float* __restrict__ flagp) {
    __shared__ int sh[64];
    int insane = 0;
    for (int i = threadIdx.x; i < 1024; i += 64) {
        unsigned int lo = (x[i] & 0xFFFFu) << 16;
        float v = __uint_as_float(lo);
        if (!(fabsf(v) <= 1e6f)) insane++;
    }
    sh[threadIdx.x] = insane;
    __syncthreads();
    if (threadIdx.x == 0) {
        int t = 0;
        for (int i = 0; i < 64; ++i) t += sh[i];
        *flagp = (t < 16) ? 1.f : 0.f;            // 1 => inputs are bf16
    }
}

// ---------------------------------------------------------------- diagnostic fill
__global__ void diag_fill(unsigned int* __restrict__ out, int nwords, float val) {
    int i = blockIdx.x * blockDim.x + threadIdx.x;
    if (i < nwords) {
        unsigned short h = (unsigned short)(__float_as_uint(val) >> 16);
        out[i] = ((unsigned int)h << 16) | h;
    }
}

// ---------------------------------------------------------------- 2x2 mean pool (input -> bf16 ws)
__global__ void pool2_kernel(const void* __restrict__ in, const float* __restrict__ flg,
                             bf16* __restrict__ out, int BC, int H2, int W2) {
    bool isb = (*flg != 0.f);
    int idx = blockIdx.x * blockDim.x + threadIdx.x;
    int total = BC * H2 * W2;
    if (idx >= total) return;
    int p  = idx % (H2 * W2);
    int bc = idx / (H2 * W2);
    int h = p / W2, w = p % W2;
    int W = 2 * W2;
    size_t base = (size_t)bc * (4 * H2 * W2);
    float s = ldin(in, base + (2*h)*W + 2*w, isb)     + ldin(in, base + (2*h)*W + 2*w + 1, isb)
            + ldin(in, base + (2*h+1)*W + 2*w, isb)   + ldin(in, base + (2*h+1)*W + 2*w + 1, isb);
    out[idx] = f2b(0.25f * s);
}

// ---------------------------------------------------------------- MFMA implicit-GEMM conv3x3
// Block: 16x16 spatial tile x 16 output channels, 256 threads (4 waves).
// Per ci-chunk of 32: stage input halo tile (18x18, ci-stride 40 for 16B-aligned
// conflict-free ds_read_b128) + weights [tap][co][ci40]; K-loop: 9 taps x
// (B-frag + 4 m-tiles x (A-frag + mfma_f32_16x16x32_bf16)).
// Fragments: A[m=lane&15][k=quad*8+j], B[n=lane&15][k=quad*8+j],
//            D[col=lane&15 -> co][row=quad*4+reg -> px-col], m-tile t -> spatial row wave*4+t.
// Requires: H,W multiples of 16; Cin multiple of 32; Cout multiple of 16 (all hold here).
// grid = (H/16 * W/16, Cout/16, B). modeX: 1 = external input (flag dtype), 0 = ws bf16.
#define CIB 40
__global__ __launch_bounds__(256, 4) void conv3x3_mfma(
        const void* __restrict__ in1, int C1, int mode1,
        const void* __restrict__ in2, int C2, int mode2,
        const void* __restrict__ wt,
        const void* __restrict__ bias,
        const void* __restrict__ alpha,
        const float* __restrict__ flg,
        bf16* __restrict__ out,
        int H, int W, int Cout, int act) {
    __shared__ bf16 in_s[18 * 18 * CIB];    // [(row*18+col)*CIB + ci]
    __shared__ bf16 w_s[9 * 16 * CIB];      // [(tap*16+co)*CIB + ci]

    const bool isb = (*flg != 0.f);
    const bool bi1 = mode1 ? isb : true;
    const bool bi2 = mode2 ? isb : true;
    const int Cin = C1 + C2;
    const int b = blockIdx.z;
    const int tiles_w = W >> 4;
    const int tile_r = (blockIdx.x / tiles_w) << 4;
    const int tile_c = (blockIdx.x % tiles_w) << 4;
    const int co_base = blockIdx.y << 4;

    const int tid  = threadIdx.x;
    const int wave = tid >> 6;
    const int lane = tid & 63;
    const int quad = lane >> 4;
    const int l16  = lane & 15;

    // acc init with bias: D col (=lane&15) is the co index.
    float bv = ldin(bias, co_base + l16, isb);
    f32x4 acc[4];
    #pragma unroll
    for (int t = 0; t < 4; ++t) { acc[t][0] = bv; acc[t][1] = bv; acc[t][2] = bv; acc[t][3] = bv; }

    for (int ci0 = 0; ci0 < Cin; ci0 += 32) {
        __syncthreads();
        // ---- stage input 18x18x32 (zero-pad halo), col-fastest for coalescing
        for (int idx = tid; idx < 18 * 18 * 32; idx += 256) {
            int col = idx % 18;
            int row = (idx / 18) % 18;
            int ci  = idx / 324;
            int gh = tile_r + row - 1, gw = tile_c + col - 1;
            float v = 0.f;
            if (gh >= 0 && gh < H && gw >= 0 && gw < W) {
                int cig = ci0 + ci;
                if (cig < C1)
                    v = ldin(in1, ((size_t)(b * C1 + cig)) * H * W + (size_t)gh * W + gw, bi1);
                else
                    v = ldin(in2, ((size_t)(b * C2 + (cig - C1))) * H * W + (size_t)gh * W + gw, bi2);
            }
            in_s[(row * 18 + col) * CIB + ci] = f2b(v);
        }
        // ---- stage weights [tap][co][ci] for this (co16, ci32)
        for (int idx = tid; idx < 9 * 16 * 32; idx += 256) {
            int ci  = idx & 31;
            int co  = (idx >> 5) & 15;
            int tap = idx >> 9;
            float v = ldin(wt, ((size_t)(co_base + co) * Cin + ci0 + ci) * 9 + tap, isb);
            w_s[(tap * 16 + co) * CIB + ci] = f2b(v);
        }
        __syncthreads();

        #pragma unroll
        for (int tap = 0; tap < 9; ++tap) {
            const int kh = tap / 3, kw = tap % 3;
            short8 bfrag = *(const short8*)&w_s[(tap * 16 + l16) * CIB + quad * 8];
            #pragma unroll
            for (int t = 0; t < 4; ++t) {
                int R = (wave << 2) + t;         // spatial row within tile
                short8 afrag = *(const short8*)&in_s[((R + kh) * 18 + l16 + kw) * CIB + quad * 8];
                acc[t] = __builtin_amdgcn_mfma_f32_16x16x32_bf16(afrag, bfrag, acc[t], 0, 0, 0);
            }
        }
    }

    // ---- epilogue: activation + store. D: col=l16 -> co, row=quad*4+reg -> px col.
    const int cog = co_base + l16;
    float a = (act == 2) ? ldin(alpha, cog, isb) : 0.f;
    bf16* op = out + ((size_t)(b * Cout + cog)) * H * W;
    #pragma unroll
    for (int t = 0; t < 4; ++t) {
        int gr = tile_r + (wave << 2) + t;
        #pragma unroll
        for (int reg = 0; reg < 4; ++reg) {
            float v = acc[t][reg];
            if (act == 1) v = fmaxf(v, 0.f);
            else if (act == 2) v = (v >= 0.f) ? v : a * v;
            op[(size_t)gr * W + tile_c + (quad << 2) + reg] = f2b(v);
        }
    }
}

// ---------------------------------------------------------------- fused CAUN tail
__global__ void caun_kernel(const bf16* __restrict__ f,
                            const void* __restrict__ xlow, int modex,
                            const void* __restrict__ kw,
                            const void* __restrict__ kb,
                            const float* __restrict__ flg,
                            bf16* __restrict__ out,
                            int C, int K, int H, int W) {
    extern __shared__ float sm[];           // 36*K weights + 36 bias
    bool isb = (*flg != 0.f);
    bool bx = modex ? isb : true;
    float* kws = sm;
    float* kbs = sm + 36 * K;
    int bc = blockIdx.y;
    int b = bc / C, c = bc % C;
    for (int i = threadIdx.x; i < 36 * K; i += blockDim.x)
        kws[i] = ldin(kw, (size_t)(c * 36) * K + i, isb);
    for (int i = threadIdx.x; i < 36; i += blockDim.x)
        kbs[i] = ldin(kb, c * 36 + i, isb);
    __syncthreads();

    int p = blockIdx.x * blockDim.x + threadIdx.x;
    if (p >= H * W) return;
    int h = p / W, w = p % W;

    float logits[36];
    #pragma unroll
    for (int j = 0; j < 36; ++j) logits[j] = kbs[j];

    const bf16* fp = f + (size_t)b * K * H * W + p;
    for (int k = 0; k < K; ++k) {
        float fv = b2f(fp[(size_t)k * H * W]);
        const float* kr = kws + k;
        #pragma unroll
        for (int j = 0; j < 36; ++j)
            logits[j] = fmaf(fv, kr[j * K], logits[j]);
    }

    float neigh[9];
    size_t xbase = (size_t)(b * C + c) * H * W;
    #pragma unroll
    for (int n = 0; n < 9; ++n) {
        int ih = h + n / 3 - 1; ih = min(max(ih, 0), H - 1);
        int iw = w + n % 3 - 1; iw = min(max(iw, 0), W - 1);
        neigh[n] = ldin(xlow, xbase + (size_t)ih * W + iw, bx);
    }

    bf16* op = out + (size_t)(b * C + c) * 4 * H * W;
    #pragma unroll
    for (int u = 0; u < 2; ++u) {
        #pragma unroll
        for (int v = 0; v < 2; ++v) {
            int g = u * 2 + v;
            float mx = -1e30f;
            #pragma unroll
            for (int n = 0; n < 9; ++n) mx = fmaxf(mx, logits[n * 4 + g]);
            float se = 0.f, acc = 0.f;
            #pragma unroll
            for (int n = 0; n < 9; ++n) {
                float e = expf(logits[n * 4 + g] - mx);
                se += e;
                acc = fmaf(e, neigh[n], acc);
            }
            int L = ((w * 2 + v) * H + h) * 2 + u;   // torch permute(0,1,5,3,4,2)
            op[L] = f2b(acc / se);
        }
    }
}

// ---------------------------------------------------------------- memory bank: row-l2norm of mem
__global__ void memnorm_kernel(const void* __restrict__ mem, const float* __restrict__ flg,
                               float* __restrict__ mn) {
    bool isb = (*flg != 0.f);
    int s = threadIdx.x;          // 64 slots
    float v[32];
    float ss = 0.f;
    #pragma unroll
    for (int c = 0; c < 32; ++c) { v[c] = ldin(mem, s * 32 + c, isb); ss += v[c] * v[c]; }
    float inv = 1.f / fmaxf(sqrtf(ss), 1e-12f);
    #pragma unroll
    for (int c = 0; c < 32; ++c) mn[s * 32 + c] = v[c] * inv;
}

// ---------------------------------------------------------------- memory fusion (in place, bf16 ws)
// Dots of two unit vectors are in [-1,1] -> exp() safe without max subtraction.
__global__ __launch_bounds__(256, 2) void memfuse_kernel(
        bf16* __restrict__ x, const float* __restrict__ mn, int HW) {
    __shared__ float mns[64 * 32];
    for (int i = threadIdx.x; i < 64 * 32; i += blockDim.x) mns[i] = mn[i];
    __syncthreads();
    int idx = blockIdx.x * blockDim.x + threadIdx.x;   // over B*HW
    int b = idx / HW, p = idx % HW;
    bf16* xp = x + (size_t)b * 32 * HW + p;

    float feat[32];
    float ss = 0.f;
    #pragma unroll
    for (int c = 0; c < 32; ++c) { feat[c] = b2f(xp[(size_t)c * HW]); ss += feat[c] * feat[c]; }
    float inv = 1.f / fmaxf(sqrtf(ss), 1e-12f);

    float se = 0.f;
    float racc[32];
    #pragma unroll
    for (int c = 0; c < 32; ++c) racc[c] = 0.f;

    for (int s = 0; s < 64; ++s) {
        const float* mr = mns + s * 32;
        float dot = 0.f;
        #pragma unroll
        for (int c = 0; c < 32; ++c) dot = fmaf(feat[c], mr[c], dot);
        float e = expf(dot * inv);
        se += e;
        #pragma unroll
        for (int c = 0; c < 32; ++c) racc[c] = fmaf(e, mr[c], racc[c]);
    }
    float rse = 1.f / se;
    #pragma unroll
    for (int c = 0; c < 32; ++c)
        xp[(size_t)c * HW] = f2b(feat[c] + racc[c] * rse);
}

// ---------------------------------------------------------------- final 1x1 conv 32 -> 2
__global__ void final1x1_kernel(const bf16* __restrict__ x,
                                const void* __restrict__ fw, const void* __restrict__ fb,
                                const float* __restrict__ flg,
                                void* __restrict__ out, int HW) {
    bool isb = (*flg != 0.f);
    int idx = blockIdx.x * blockDim.x + threadIdx.x;   // over B*HW
    int b = idx / HW, p = idx % HW;
    const bf16* xp = x + (size_t)b * 32 * HW + p;
    float a0 = ldin(fb, 0, isb), a1 = ldin(fb, 1, isb);
    #pragma unroll
    for (int c = 0; c < 32; ++c) {
        float v = b2f(xp[(size_t)c * HW]);
        a0 = fmaf(v, ldin(fw, c, isb), a0);
        a1 = fmaf(v, ldin(fw, 32 + c, isb), a1);
    }
    size_t i0 = (size_t)b * 2 * HW + p;
    size_t i1 = i0 + HW;
    if (isb) { ((bf16*)out)[i0] = f2b(a0); ((bf16*)out)[i1] = f2b(a1); }
    else     { ((float*)out)[i0] = a0;     ((float*)out)[i1] = a1; }
}

// ================================================================ host
extern "C" void kernel_launch(void* const* d_in, const int* in_sizes, int n_in,
                              void* d_out, int out_size, void* d_ws, size_t ws_size,
                              hipStream_t stream) {
    const void* x0_0 = d_in[0];
    const void* x1_0 = d_in[1];
    const void* x2_0 = d_in[2];
    const void* x3_0 = d_in[3];
    const void* c3_w1 = d_in[4];  const void* c3_b1 = d_in[5];  const void* c3_a1 = d_in[6];
    const void* c3_w2 = d_in[7];  const void* c3_b2 = d_in[8];  const void* c3_a2 = d_in[9];
    const void* c3_kw = d_in[10]; const void* c3_kb = d_in[11];
    const void* c2_w1 = d_in[12]; const void* c2_b1 = d_in[13]; const void* c2_a1 = d_in[14];
    const void* c2_w2 = d_in[15]; const void* c2_b2 = d_in[16]; const void* c2_a2 = d_in[17];
    const void* c2_kw = d_in[18]; const void* c2_kb = d_in[19];
    const void* c1_w1 = d_in[20]; const void* c1_b1 = d_in[21]; const void* c1_a1 = d_in[22];
    const void* c1_w2 = d_in[23]; const void* c1_b2 = d_in[24]; const void* c1_a2 = d_in[25];
    const void* c1_kw = d_in[26]; const void* c1_kb = d_in[27];
    const void* b21_w1 = d_in[28]; const void* b21_b1 = d_in[29];
    const void* b21_w2 = d_in[30]; const void* b21_b2 = d_in[31];
    const void* b12_w1 = d_in[32]; const void* b12_b1 = d_in[33];
    const void* b12_w2 = d_in[34]; const void* b12_b2 = d_in[35];
    const void* b03_w1 = d_in[36]; const void* b03_b1 = d_in[37];
    const void* b03_w2 = d_in[38]; const void* b03_b2 = d_in[39];
    const void* fin_w = d_in[40];  const void* fin_b = d_in[41];
    const void* memw  = d_in[42];
    (void)in_sizes; (void)n_in;

    const int TB = 256;
    auto blocks = [](int n) { return (n + 255) / 256; };

    const size_t NEED = 25165824 + 65536;
    if (ws_size < NEED) {
        diag_fill<<<blocks(out_size / 2), TB, 0, stream>>>(
            (unsigned int*)d_out, out_size / 2, (float)ws_size);
        return;
    }
    size_t tail = (ws_size - 65536) & ~(size_t)255;
    float* mn  = (float*)((char*)d_ws + tail);          // 8 KB
    float* flg = (float*)((char*)d_ws + tail + 8192);   // 4 B

    // 24 MiB arena, hand-verified live-range plan (offsets in bf16 elements):
    bf16* A = (bf16*)d_ws;
    bf16* x3up  = A + 0;
    bf16* ctx3p = A + 2097152;
    bf16* f3a   = A + 2359296;
    bf16* f3b   = A + 2621440;
    bf16* t2a   = A + 2097152;
    bf16* x2_1  = A + 0;
    bf16* ctx2  = A + 1048576;
    bf16* f2a   = A + 1572864;
    bf16* f2b   = A + 2097152;
    bf16* x2up  = A + 2359296;
    bf16* t1a   = A + 0;
    bf16* x1_2  = A + 10485760;
    bf16* ctx1  = A + 4194304;
    bf16* f1a   = A + 5242880;
    bf16* f1b   = A + 9437184;
    bf16* x1up  = A + 0;
    bf16* t0a   = A + 8388608;
    bf16* x0_3  = A + 0;

    // ---- dtype detection (writes flg)
    detect_kernel<<<1, 64, 0, stream>>>((const unsigned int*)x0_0, flg);

    // conv grid helper: (H/16 * W/16, Cout/16, 2)
    auto cgrid = [](int H, int W, int Cout) { return dim3((H >> 4) * (W >> 4), Cout >> 4, 2); };

    // ---- caun3: x3_0 [2,256,32,32], ctx = pool(x2_0) -> [2,128,32,32]
    pool2_kernel<<<blocks(262144), TB, 0, stream>>>(x2_0, flg, ctx3p, 256, 32, 32);
    conv3x3_mfma<<<cgrid(32, 32, 128), TB, 0, stream>>>(
        ctx3p, 128, 0, nullptr, 0, 0, c3_w1, c3_b1, c3_a1, flg, f3a, 32, 32, 128, 2);
    conv3x3_mfma<<<cgrid(32, 32, 64), TB, 0, stream>>>(
        f3a, 128, 0, nullptr, 0, 0, c3_w2, c3_b2, c3_a2, flg, f3b, 32, 32, 64, 2);
    caun_kernel<<<dim3(4, 512), TB, (36 * 64 + 36) * 4, stream>>>(
        f3b, x3_0, 1, c3_kw, c3_kb, flg, x3up, 256, 64, 32, 32);

    // ---- block21: cat(x2_0 [128], x3up [256]) -> 128 -> 128 @64x64
    conv3x3_mfma<<<cgrid(64, 64, 128), TB, 0, stream>>>(
        x2_0, 128, 1, x3up, 256, 0, b21_w1, b21_b1, nullptr, flg, t2a, 64, 64, 128, 1);
    conv3x3_mfma<<<cgrid(64, 64, 128), TB, 0, stream>>>(
        t2a, 128, 0, nullptr, 0, 0, b21_w2, b21_b2, nullptr, flg, x2_1, 64, 64, 128, 1);

    // ---- caun2: x2_1 [2,128,64,64], ctx = pool(x1_0) -> [2,64,64,64]
    pool2_kernel<<<blocks(524288), TB, 0, stream>>>(x1_0, flg, ctx2, 128, 64, 64);
    conv3x3_mfma<<<cgrid(64, 64, 64), TB, 0, stream>>>(
        ctx2, 64, 0, nullptr, 0, 0, c2_w1, c2_b1, c2_a1, flg, f2a, 64, 64, 64, 2);
    conv3x3_mfma<<<cgrid(64, 64, 32), TB, 0, stream>>>(
        f2a, 64, 0, nullptr, 0, 0, c2_w2, c2_b2, c2_a2, flg, f2b, 64, 64, 32, 2);
    caun_kernel<<<dim3(16, 256), TB, (36 * 32 + 36) * 4, stream>>>(
        f2b, x2_1, 0, c2_kw, c2_kb, flg, x2up, 128, 32, 64, 64);

    // ---- block12: cat(x1_0 [64], x2up [128]) -> 64 -> 64 @128x128
    conv3x3_mfma<<<cgrid(128, 128, 64), TB, 0, stream>>>(
        x1_0, 64, 1, x2up, 128, 0, b12_w1, b12_b1, nullptr, flg, t1a, 128, 128, 64, 1);
    conv3x3_mfma<<<cgrid(128, 128, 64), TB, 0, stream>>>(
        t1a, 64, 0, nullptr, 0, 0, b12_w2, b12_b2, nullptr, flg, x1_2, 128, 128, 64, 1);

    // ---- caun1: x1_2 [2,64,128,128], ctx = pool(x0_0) -> [2,32,128,128]
    pool2_kernel<<<blocks(1048576), TB, 0, stream>>>(x0_0, flg, ctx1, 64, 128, 128);
    conv3x3_mfma<<<cgrid(128, 128, 32), TB, 0, stream>>>(
        ctx1, 32, 0, nullptr, 0, 0, c1_w1, c1_b1, c1_a1, flg, f1a, 128, 128, 32, 2);
    conv3x3_mfma<<<cgrid(128, 128, 16), TB, 0, stream>>>(
        f1a, 32, 0, nullptr, 0, 0, c1_w2, c1_b2, c1_a2, flg, f1b, 128, 128, 16, 2);
    caun_kernel<<<dim3(64, 128), TB, (36 * 16 + 36) * 4, stream>>>(
        f1b, x1_2, 0, c1_kw, c1_kb, flg, x1up, 64, 16, 128, 128);

    // ---- block03: cat(x0_0 [32], x1up [64]) -> 32 -> 32 @256x256
    conv3x3_mfma<<<cgrid(256, 256, 32), TB, 0, stream>>>(
        x0_0, 32, 1, x1up, 64, 0, b03_w1, b03_b1, nullptr, flg, t0a, 256, 256, 32, 1);
    conv3x3_mfma<<<cgrid(256, 256, 32), TB, 0, stream>>>(
        t0a, 32, 0, nullptr, 0, 0, b03_w2, b03_b2, nullptr, flg, x0_3, 256, 256, 32, 1);

    // ---- memory-bank residual fusion (in place) + final 1x1 conv -> [2,2,256,256]
    memnorm_kernel<<<1, 64, 0, stream>>>(memw, flg, mn);
    memfuse_kernel<<<512, TB, 0, stream>>>(x0_3, mn, 256 * 256);
    final1x1_kernel<<<512, TB, 0, stream>>>(x0_3, fin_w, fin_b, flg, d_out, 256 * 256);
}

// Round 9
// 1111.118 us; speedup vs baseline: 6.7996x; 1.3079x over previous
//
#include <hip/hip_runtime.h>
#include <hip/hip_bf16.h>
#include <math.h>

typedef __hip_bfloat16 bf16;
typedef short short8 __attribute__((ext_vector_type(8)));   // bf16x8 MFMA frag (4 VGPRs)
typedef float f32x4 __attribute__((ext_vector_type(4)));    // MFMA accumulator

static __device__ __forceinline__ float b2f(bf16 x) { return __bfloat162float(x); }
static __device__ __forceinline__ bf16  f2b(float x) { return __float2bfloat16(x); }
static __device__ __forceinline__ short f2bs(float x) { bf16 t = f2b(x); return *reinterpret_cast<short*>(&t); }

// Polymorphic input load: isb=true -> bf16 storage, else f32 storage.
static __device__ __forceinline__ float ldin(const void* p, size_t i, bool isb) {
    return isb ? b2f(((const bf16*)p)[i]) : ((const float*)p)[i];
}

// ---------------------------------------------------------------- dtype detect
__global__ void detect_kernel(const unsigned int* __restrict__ x, float* __restrict__ flagp) {
    __shared__ int sh[64];
    int insane = 0;
    for (int i = threadIdx.x; i < 1024; i += 64) {
        unsigned int lo = (x[i] & 0xFFFFu) << 16;
        float v = __uint_as_float(lo);
        if (!(fabsf(v) <= 1e6f)) insane++;
    }
    sh[threadIdx.x] = insane;
    __syncthreads();
    if (threadIdx.x == 0) {
        int t = 0;
        for (int i = 0; i < 64; ++i) t += sh[i];
        *flagp = (t < 16) ? 1.f : 0.f;            // 1 => inputs are bf16
    }
}

// ---------------------------------------------------------------- diagnostic fill
__global__ void diag_fill(unsigned int* __restrict__ out, int nwords, float val) {
    int i = blockIdx.x * blockDim.x + threadIdx.x;
    if (i < nwords) {
        unsigned short h = (unsigned short)(__float_as_uint(val) >> 16);
        out[i] = ((unsigned int)h << 16) | h;
    }
}

// ---------------------------------------------------------------- weight pack: [co][ci][tap] -> [tap][co][ci] bf16
__global__ void wpack_kernel(const void* __restrict__ wt, const float* __restrict__ flg,
                             bf16* __restrict__ dst, int Cout, int Cin) {
    bool isb = (*flg != 0.f);
    int n = Cout * Cin * 9;
    int idx = blockIdx.x * blockDim.x + threadIdx.x;
    if (idx >= n) return;
    int ci = idx % Cin;
    int co = (idx / Cin) % Cout;
    int tap = idx / (Cin * Cout);
    dst[idx] = f2b(ldin(wt, ((size_t)co * Cin + ci) * 9 + tap, isb));
}

// ---------------------------------------------------------------- 2x2 mean pool: NCHW ext -> channels-last bf16 ws
__global__ void pool2_cl(const void* __restrict__ in, const float* __restrict__ flg,
                         bf16* __restrict__ out, int B, int C, int H2, int W2) {
    bool isb = (*flg != 0.f);
    int idx = blockIdx.x * blockDim.x + threadIdx.x;
    int total = B * H2 * W2 * C;
    if (idx >= total) return;
    int c = idx % C;
    int pix = idx / C;
    int w = pix % W2;
    int h = (pix / W2) % H2;
    int b = pix / (W2 * H2);
    int H = H2 * 2, W = W2 * 2;
    size_t base = ((size_t)(b * C + c)) * H * W;
    float s = ldin(in, base + (size_t)(2*h)*W + 2*w, isb)   + ldin(in, base + (size_t)(2*h)*W + 2*w + 1, isb)
            + ldin(in, base + (size_t)(2*h+1)*W + 2*w, isb) + ldin(in, base + (size_t)(2*h+1)*W + 2*w + 1, isb);
    out[idx] = f2b(0.25f * s);
}

// ---------------------------------------------------------------- MFMA conv3x3, channels-last, no LDS
// Wave = 16-px row segment x 16 co. A/B frags are direct 16B global loads.
// in1: external NCHW (dtype flag), first C1 channels (8 scalar loads/frag, lines
// shared across pixel-lanes). in2: ws channels-last bf16, C2 channels.
// wp: packed [tap][Cout][Cin] bf16. out: channels-last bf16 [B][H][W][Cout].
// grid = (W/16, H/4, B * Cout/16), block 256 = 4 waves (wave w -> row blockIdx.y*4+w).
// Fragments (verified round 8): A[m=l16 -> pixel][k=quad*8+j], B[n=l16 -> co][k],
// D[col=l16 -> co][row=quad*4+reg -> pixel]. Requires C1,C2 multiples of 32 (or 0).
__global__ __launch_bounds__(256) void conv3x3_cl(
        const void* __restrict__ in1, int C1,
        const bf16* __restrict__ in2, int C2,
        const bf16* __restrict__ wp,
        const void* __restrict__ bias,
        const void* __restrict__ alpha,
        const float* __restrict__ flg,
        bf16* __restrict__ out,
        int H, int W, int Cout, int act) {
    const bool isb = (*flg != 0.f);
    const int Cin = C1 + C2;
    const int lane = threadIdx.x & 63;
    const int wave = threadIdx.x >> 6;
    const int quad = lane >> 4, l16 = lane & 15;
    const int cot = Cout >> 4;
    const int b = blockIdx.z / cot;
    const int co_base = (blockIdx.z % cot) << 4;
    const int r = (blockIdx.y << 2) + wave;
    const int c0 = blockIdx.x << 4;
    const int cog = co_base + l16;

    float bv = ldin(bias, cog, isb);
    f32x4 acc = {bv, bv, bv, bv};

    for (int ci0 = 0; ci0 < Cin; ci0 += 32) {
        const bool ext = (ci0 < C1);
        #pragma unroll
        for (int tap = 0; tap < 9; ++tap) {
            const int ih = r + tap / 3 - 1;
            const int iw = c0 + l16 + tap % 3 - 1;
            const bool ok = (ih >= 0) && (ih < H) && (iw >= 0) && (iw < W);
            short8 bfrag = *(const short8*)&wp[((size_t)tap * Cout + cog) * Cin + ci0 + quad * 8];
            short8 afrag = {0, 0, 0, 0, 0, 0, 0, 0};
            if (ext) {
                if (ok) {
                    size_t base = ((size_t)(b * C1 + ci0 + quad * 8)) * H * W + (size_t)ih * W + iw;
                    #pragma unroll
                    for (int j = 0; j < 8; ++j)
                        afrag[j] = f2bs(ldin(in1, base + (size_t)j * H * W, isb));
                }
            } else {
                if (ok)
                    afrag = *(const short8*)&in2[(((size_t)(b * H) + ih) * W + iw) * C2
                                                 + (ci0 - C1) + quad * 8];
            }
            acc = __builtin_amdgcn_mfma_f32_16x16x32_bf16(afrag, bfrag, acc, 0, 0, 0);
        }
    }

    float a = (act == 2) ? ldin(alpha, cog, isb) : 0.f;
    #pragma unroll
    for (int reg = 0; reg < 4; ++reg) {
        float v = acc[reg];
        if (act == 1) v = fmaxf(v, 0.f);
        else if (act == 2) v = (v >= 0.f) ? v : a * v;
        out[(((size_t)(b * H) + r) * W + c0 + (quad << 2) + reg) * Cout + cog] = f2b(v);
    }
}

// ---------------------------------------------------------------- fused CAUN tail (f channels-last)
// xext: 1 = xlow external NCHW (dtype flag), 0 = xlow ws channels-last bf16.
// out: channels-last bf16 [B][2H][2W][C] via torch-faithful scrambled L.
__global__ void caun_kernel(const bf16* __restrict__ f,
                            const void* __restrict__ xlow, int xext,
                            const void* __restrict__ kw,
                            const void* __restrict__ kb,
                            const float* __restrict__ flg,
                            bf16* __restrict__ out,
                            int C, int K, int H, int W) {
    extern __shared__ float sm[];           // 36*K weights + 36 bias
    bool isb = (*flg != 0.f);
    float* kws = sm;
    float* kbs = sm + 36 * K;
    int bc = blockIdx.y;
    int b = bc / C, c = bc % C;
    for (int i = threadIdx.x; i < 36 * K; i += blockDim.x)
        kws[i] = ldin(kw, (size_t)(c * 36) * K + i, isb);
    for (int i = threadIdx.x; i < 36; i += blockDim.x)
        kbs[i] = ldin(kb, c * 36 + i, isb);
    __syncthreads();

    int p = blockIdx.x * blockDim.x + threadIdx.x;
    if (p >= H * W) return;
    int h = p / W, w = p % W;

    float logits[36];
    #pragma unroll
    for (int j = 0; j < 36; ++j) logits[j] = kbs[j];

    const bf16* fp = f + (((size_t)(b * H) + h) * W + w) * K;   // contiguous K
    for (int k = 0; k < K; ++k) {
        float fv = b2f(fp[k]);
        const float* kr = kws + k;
        #pragma unroll
        for (int j = 0; j < 36; ++j)
            logits[j] = fmaf(fv, kr[j * K], logits[j]);
    }

    float neigh[9];
    #pragma unroll
    for (int n = 0; n < 9; ++n) {
        int ih = h + n / 3 - 1; ih = min(max(ih, 0), H - 1);
        int iw = w + n % 3 - 1; iw = min(max(iw, 0), W - 1);
        neigh[n] = xext
            ? ldin(xlow, ((size_t)(b * C + c)) * H * W + (size_t)ih * W + iw, isb)
            : b2f(((const bf16*)xlow)[(((size_t)(b * H) + ih) * W + iw) * C + c]);
    }

    bf16* op = out + ((size_t)b * 4 * H * W) * C + c;
    #pragma unroll
    for (int u = 0; u < 2; ++u) {
        #pragma unroll
        for (int v = 0; v < 2; ++v) {
            int g = u * 2 + v;
            float mx = -1e30f;
            #pragma unroll
            for (int n = 0; n < 9; ++n) mx = fmaxf(mx, logits[n * 4 + g]);
            float se = 0.f, acc = 0.f;
            #pragma unroll
            for (int n = 0; n < 9; ++n) {
                float e = expf(logits[n * 4 + g] - mx);
                se += e;
                acc = fmaf(e, neigh[n], acc);
            }
            size_t L = ((size_t)(w * 2 + v) * H + h) * 2 + u;   // torch permute(0,1,5,3,4,2)
            op[L * C] = f2b(acc / se);
        }
    }
}

// ---------------------------------------------------------------- memory bank: row-l2norm of mem
__global__ void memnorm_kernel(const void* __restrict__ mem, const float* __restrict__ flg,
                               float* __restrict__ mn) {
    bool isb = (*flg != 0.f);
    int s = threadIdx.x;          // 64 slots
    float v[32];
    float ss = 0.f;
    #pragma unroll
    for (int c = 0; c < 32; ++c) { v[c] = ldin(mem, s * 32 + c, isb); ss += v[c] * v[c]; }
    float inv = 1.f / fmaxf(sqrtf(ss), 1e-12f);
    #pragma unroll
    for (int c = 0; c < 32; ++c) mn[s * 32 + c] = v[c] * inv;
}

// ---------------------------------------------------------------- memory fusion (in place, channels-last bf16 ws)
__global__ __launch_bounds__(256, 2) void memfuse_kernel(
        bf16* __restrict__ x, const float* __restrict__ mn) {
    __shared__ float mns[64 * 32];
    for (int i = threadIdx.x; i < 64 * 32; i += blockDim.x) mns[i] = mn[i];
    __syncthreads();
    int idx = blockIdx.x * blockDim.x + threadIdx.x;   // over B*HW
    bf16* xp = x + (size_t)idx * 32;

    float feat[32];
    float ss = 0.f;
    #pragma unroll
    for (int c = 0; c < 32; ++c) { feat[c] = b2f(xp[c]); ss += feat[c] * feat[c]; }
    float inv = 1.f / fmaxf(sqrtf(ss), 1e-12f);

    float se = 0.f;
    float racc[32];
    #pragma unroll
    for (int c = 0; c < 32; ++c) racc[c] = 0.f;

    for (int s = 0; s < 64; ++s) {
        const float* mr = mns + s * 32;
        float dot = 0.f;
        #pragma unroll
        for (int c = 0; c < 32; ++c) dot = fmaf(feat[c], mr[c], dot);
        float e = expf(dot * inv);     // dot*inv in [-1,1] -> exp safe unshifted
        se += e;
        #pragma unroll
        for (int c = 0; c < 32; ++c) racc[c] = fmaf(e, mr[c], racc[c]);
    }
    float rse = 1.f / se;
    #pragma unroll
    for (int c = 0; c < 32; ++c)
        xp[c] = f2b(feat[c] + racc[c] * rse);
}

// ---------------------------------------------------------------- final 1x1 conv 32 -> 2 (x channels-last)
__global__ void final1x1_kernel(const bf16* __restrict__ x,
                                const void* __restrict__ fw, const void* __restrict__ fb,
                                const float* __restrict__ flg,
                                void* __restrict__ out, int HW) {
    bool isb = (*flg != 0.f);
    int idx = blockIdx.x * blockDim.x + threadIdx.x;   // over B*HW
    int b = idx / HW, p = idx % HW;
    const bf16* xp = x + (size_t)idx * 32;
    float a0 = ldin(fb, 0, isb), a1 = ldin(fb, 1, isb);
    #pragma unroll
    for (int c = 0; c < 32; ++c) {
        float v = b2f(xp[c]);
        a0 = fmaf(v, ldin(fw, c, isb), a0);
        a1 = fmaf(v, ldin(fw, 32 + c, isb), a1);
    }
    size_t i0 = (size_t)b * 2 * HW + p;
    size_t i1 = i0 + HW;
    if (isb) { ((bf16*)out)[i0] = f2b(a0); ((bf16*)out)[i1] = f2b(a1); }
    else     { ((float*)out)[i0] = a0;     ((float*)out)[i1] = a1; }
}

// ================================================================ host
extern "C" void kernel_launch(void* const* d_in, const int* in_sizes, int n_in,
                              void* d_out, int out_size, void* d_ws, size_t ws_size,
                              hipStream_t stream) {
    const void* x0_0 = d_in[0];
    const void* x1_0 = d_in[1];
    const void* x2_0 = d_in[2];
    const void* x3_0 = d_in[3];
    const void* c3_w1 = d_in[4];  const void* c3_b1 = d_in[5];  const void* c3_a1 = d_in[6];
    const void* c3_w2 = d_in[7];  const void* c3_b2 = d_in[8];  const void* c3_a2 = d_in[9];
    const void* c3_kw = d_in[10]; const void* c3_kb = d_in[11];
    const void* c2_w1 = d_in[12]; const void* c2_b1 = d_in[13]; const void* c2_a1 = d_in[14];
    const void* c2_w2 = d_in[15]; const void* c2_b2 = d_in[16]; const void* c2_a2 = d_in[17];
    const void* c2_kw = d_in[18]; const void* c2_kb = d_in[19];
    const void* c1_w1 = d_in[20]; const void* c1_b1 = d_in[21]; const void* c1_a1 = d_in[22];
    const void* c1_w2 = d_in[23]; const void* c1_b2 = d_in[24]; const void* c1_a2 = d_in[25];
    const void* c1_kw = d_in[26]; const void* c1_kb = d_in[27];
    const void* b21_w1 = d_in[28]; const void* b21_b1 = d_in[29];
    const void* b21_w2 = d_in[30]; const void* b21_b2 = d_in[31];
    const void* b12_w1 = d_in[32]; const void* b12_b1 = d_in[33];
    const void* b12_w2 = d_in[34]; const void* b12_b2 = d_in[35];
    const void* b03_w1 = d_in[36]; const void* b03_b1 = d_in[37];
    const void* b03_w2 = d_in[38]; const void* b03_b2 = d_in[39];
    const void* fin_w = d_in[40];  const void* fin_b = d_in[41];
    const void* memw  = d_in[42];
    (void)in_sizes; (void)n_in;

    const int TB = 256;
    auto blocks = [](int n) { return (n + 255) / 256; };

    const size_t NEED = 25165824 + 65536;
    if (ws_size < NEED) {
        diag_fill<<<blocks(out_size / 2), TB, 0, stream>>>(
            (unsigned int*)d_out, out_size / 2, (float)ws_size);
        return;
    }
    // tail (>= 65,280B): [0,55296) b03 weight slot, [55296,63488) mn, [63488,+4) flg
    size_t tail = (ws_size - 65536) & ~(size_t)255;
    bf16*  wtail = (bf16*)((char*)d_ws + tail);
    float* mn    = (float*)((char*)d_ws + tail + 55296);
    float* flg   = (float*)((char*)d_ws + tail + 63488);

    // 24 MiB arena (12,582,912 bf16 elems), channels-last, round-5 verified live ranges.
    // wslot [6,553,600, 6,995,968) is free during every conv except b03 (tail slot).
    bf16* A = (bf16*)d_ws;
    bf16* x3up  = A + 0;         // [2,64,64,256]
    bf16* ctx3p = A + 2097152;   // [2,32,32,128]
    bf16* f3a   = A + 2359296;   // [2,32,32,128]
    bf16* f3b   = A + 2621440;   // [2,32,32,64]
    bf16* t2a   = A + 2097152;   // [2,64,64,128]
    bf16* x2_1  = A + 0;         // [2,64,64,128]
    bf16* ctx2  = A + 1048576;   // [2,64,64,64]
    bf16* f2a   = A + 1572864;   // [2,64,64,64]
    bf16* f2b   = A + 2097152;   // [2,64,64,32]
    bf16* x2up  = A + 2359296;   // [2,128,128,128]
    bf16* t1a   = A + 0;         // [2,128,128,64]
    bf16* x1_2  = A + 10485760;  // [2,128,128,64]
    bf16* ctx1  = A + 4194304;   // [2,128,128,32]
    bf16* f1a   = A + 5242880;   // [2,128,128,32]
    bf16* f1b   = A + 9437184;   // [2,128,128,16]
    bf16* x1up  = A + 0;         // [2,256,256,64]
    bf16* t0a   = A + 8388608;   // [2,256,256,32]
    bf16* x0_3  = A + 0;         // [2,256,256,32]
    bf16* wslot = A + 6553600;   // 442,368 elems max (b21_w1)

    detect_kernel<<<1, 64, 0, stream>>>((const unsigned int*)x0_0, flg);

    auto cgrid = [](int H, int W, int Cout) { return dim3(W >> 4, H >> 2, 2 * (Cout >> 4)); };
    auto wpk = [&](const void* w, bf16* dst, int Cout, int Cin) {
        wpack_kernel<<<blocks(Cout * Cin * 9), TB, 0, stream>>>(w, flg, dst, Cout, Cin);
    };

    // ---- caun3: ctx = pool(x2_0) -> [2,32,32,128] cl
    pool2_cl<<<blocks(262144), TB, 0, stream>>>(x2_0, flg, ctx3p, 2, 128, 32, 32);
    wpk(c3_w1, wslot, 128, 128);
    conv3x3_cl<<<cgrid(32, 32, 128), TB, 0, stream>>>(
        nullptr, 0, ctx3p, 128, wslot, c3_b1, c3_a1, flg, f3a, 32, 32, 128, 2);
    wpk(c3_w2, wslot, 64, 128);
    conv3x3_cl<<<cgrid(32, 32, 64), TB, 0, stream>>>(
        nullptr, 0, f3a, 128, wslot, c3_b2, c3_a2, flg, f3b, 32, 32, 64, 2);
    caun_kernel<<<dim3(4, 512), TB, (36 * 64 + 36) * 4, stream>>>(
        f3b, x3_0, 1, c3_kw, c3_kb, flg, x3up, 256, 64, 32, 32);

    // ---- block21: cat(x2_0 ext[128], x3up cl[256]) -> 128 -> 128 @64x64
    wpk(b21_w1, wslot, 128, 384);
    conv3x3_cl<<<cgrid(64, 64, 128), TB, 0, stream>>>(
        x2_0, 128, x3up, 256, wslot, b21_b1, nullptr, flg, t2a, 64, 64, 128, 1);
    wpk(b21_w2, wslot, 128, 128);
    conv3x3_cl<<<cgrid(64, 64, 128), TB, 0, stream>>>(
        nullptr, 0, t2a, 128, wslot, b21_b2, nullptr, flg, x2_1, 64, 64, 128, 1);

    // ---- caun2: ctx = pool(x1_0) -> [2,64,64,64] cl
    pool2_cl<<<blocks(524288), TB, 0, stream>>>(x1_0, flg, ctx2, 2, 64, 64, 64);
    wpk(c2_w1, wslot, 64, 64);
    conv3x3_cl<<<cgrid(64, 64, 64), TB, 0, stream>>>(
        nullptr, 0, ctx2, 64, wslot, c2_b1, c2_a1, flg, f2a, 64, 64, 64, 2);
    wpk(c2_w2, wslot, 32, 64);
    conv3x3_cl<<<cgrid(64, 64, 32), TB, 0, stream>>>(
        nullptr, 0, f2a, 64, wslot, c2_b2, c2_a2, flg, f2b, 64, 64, 32, 2);
    caun_kernel<<<dim3(16, 256), TB, (36 * 32 + 36) * 4, stream>>>(
        f2b, x2_1, 0, c2_kw, c2_kb, flg, x2up, 128, 32, 64, 64);

    // ---- block12: cat(x1_0 ext[64], x2up cl[128]) -> 64 -> 64 @128x128
    wpk(b12_w1, wslot, 64, 192);
    conv3x3_cl<<<cgrid(128, 128, 64), TB, 0, stream>>>(
        x1_0, 64, x2up, 128, wslot, b12_b1, nullptr, flg, t1a, 128, 128, 64, 1);
    wpk(b12_w2, wslot, 64, 64);
    conv3x3_cl<<<cgrid(128, 128, 64), TB, 0, stream>>>(
        nullptr, 0, t1a, 64, wslot, b12_b2, nullptr, flg, x1_2, 128, 128, 64, 1);

    // ---- caun1: ctx = pool(x0_0) -> [2,128,128,32] cl
    pool2_cl<<<blocks(1048576), TB, 0, stream>>>(x0_0, flg, ctx1, 2, 32, 128, 128);
    wpk(c1_w1, wslot, 32, 32);
    conv3x3_cl<<<cgrid(128, 128, 32), TB, 0, stream>>>(
        nullptr, 0, ctx1, 32, wslot, c1_b1, c1_a1, flg, f1a, 128, 128, 32, 2);
    wpk(c1_w2, wslot, 16, 32);
    conv3x3_cl<<<cgrid(128, 128, 16), TB, 0, stream>>>(
        nullptr, 0, f1a, 32, wslot, c1_b2, c1_a2, flg, f1b, 128, 128, 16, 2);
    caun_kernel<<<dim3(64, 128), TB, (36 * 16 + 36) * 4, stream>>>(
        f1b, x1_2, 0, c1_kw, c1_kb, flg, x1up, 64, 16, 128, 128);

    // ---- block03: cat(x0_0 ext[32], x1up cl[64]) -> 32 -> 32 @256x256  (weights in tail slot)
    wpk(b03_w1, wtail, 32, 96);
    conv3x3_cl<<<cgrid(256, 256, 32), TB, 0, stream>>>(
        x0_0, 32, x1up, 64, wtail, b03_b1, nullptr, flg, t0a, 256, 256, 32, 1);
    wpk(b03_w2, wtail, 32, 32);
    conv3x3_cl<<<cgrid(256, 256, 32), TB, 0, stream>>>(
        nullptr, 0, t0a, 32, wtail, b03_b2, nullptr, flg, x0_3, 256, 256, 32, 1);

    // ---- memory-bank residual fusion (in place, cl) + final 1x1 conv -> [2,2,256,256]
    memnorm_kernel<<<1, 64, 0, stream>>>(memw, flg, mn);
    memfuse_kernel<<<512, TB, 0, stream>>>(x0_3, mn);
    final1x1_kernel<<<512, TB, 0, stream>>>(x0_3, fin_w, fin_b, flg, d_out, 256 * 256);
}

// Round 10
// 1007.958 us; speedup vs baseline: 7.4955x; 1.1023x over previous
//
#include <hip/hip_runtime.h>
#include <hip/hip_bf16.h>
#include <math.h>

typedef __hip_bfloat16 bf16;
typedef short short8 __attribute__((ext_vector_type(8)));   // bf16x8 MFMA frag (4 VGPRs)
typedef float f32x4 __attribute__((ext_vector_type(4)));    // MFMA accumulator

static __device__ __forceinline__ float b2f(bf16 x) { return __bfloat162float(x); }
static __device__ __forceinline__ bf16  f2b(float x) { return __float2bfloat16(x); }
static __device__ __forceinline__ short f2bs(float x) { bf16 t = f2b(x); return *reinterpret_cast<short*>(&t); }

// Polymorphic input load: isb=true -> bf16 storage, else f32 storage.
static __device__ __forceinline__ float ldin(const void* p, size_t i, bool isb) {
    return isb ? b2f(((const bf16*)p)[i]) : ((const float*)p)[i];
}

// ---------------------------------------------------------------- dtype detect
__global__ void detect_kernel(const unsigned int* __restrict__ x, float* __restrict__ flagp) {
    __shared__ int sh[64];
    int insane = 0;
    for (int i = threadIdx.x; i < 1024; i += 64) {
        unsigned int lo = (x[i] & 0xFFFFu) << 16;
        float v = __uint_as_float(lo);
        if (!(fabsf(v) <= 1e6f)) insane++;
    }
    sh[threadIdx.x] = insane;
    __syncthreads();
    if (threadIdx.x == 0) {
        int t = 0;
        for (int i = 0; i < 64; ++i) t += sh[i];
        *flagp = (t < 16) ? 1.f : 0.f;            // 1 => inputs are bf16
    }
}

// ---------------------------------------------------------------- diagnostic fill
__global__ void diag_fill(unsigned int* __restrict__ out, int nwords, float val) {
    int i = blockIdx.x * blockDim.x + threadIdx.x;
    if (i < nwords) {
        unsigned short h = (unsigned short)(__float_as_uint(val) >> 16);
        out[i] = ((unsigned int)h << 16) | h;
    }
}

// ---------------------------------------------------------------- weight pack: [co][ci][tap] -> [tap][co][ci] bf16
__global__ void wpack_kernel(const void* __restrict__ wt, const float* __restrict__ flg,
                             bf16* __restrict__ dst, int Cout, int Cin) {
    bool isb = (*flg != 0.f);
    int n = Cout * Cin * 9;
    int idx = blockIdx.x * blockDim.x + threadIdx.x;
    if (idx >= n) return;
    int ci = idx % Cin;
    int co = (idx / Cin) % Cout;
    int tap = idx / (Cin * Cout);
    dst[idx] = f2b(ldin(wt, ((size_t)co * Cin + ci) * 9 + tap, isb));
}

// ---------------------------------------------------------------- 2x2 mean pool: NCHW ext -> channels-last bf16 ws
__global__ void pool2_cl(const void* __restrict__ in, const float* __restrict__ flg,
                         bf16* __restrict__ out, int B, int C, int H2, int W2) {
    bool isb = (*flg != 0.f);
    int idx = blockIdx.x * blockDim.x + threadIdx.x;
    int total = B * H2 * W2 * C;
    if (idx >= total) return;
    int c = idx % C;
    int pix = idx / C;
    int w = pix % W2;
    int h = (pix / W2) % H2;
    int b = pix / (W2 * H2);
    int H = H2 * 2, W = W2 * 2;
    size_t base = ((size_t)(b * C + c)) * H * W;
    float s = ldin(in, base + (size_t)(2*h)*W + 2*w, isb)   + ldin(in, base + (size_t)(2*h)*W + 2*w + 1, isb)
            + ldin(in, base + (size_t)(2*h+1)*W + 2*w, isb) + ldin(in, base + (size_t)(2*h+1)*W + 2*w + 1, isb);
    out[idx] = f2b(0.25f * s);
}

// ---------------------------------------------------------------- MFMA conv3x3, channels-last, no LDS
// Wave = 16-px row segment x 16 co. A/B frags are direct 16B global loads.
// Fragments (HW-verified): A[m=l16 -> pixel][k=quad*8+j], B[n=l16 -> co][k],
// D[col=l16 -> co][row=quad*4+reg -> pixel].
__global__ __launch_bounds__(256) void conv3x3_cl(
        const void* __restrict__ in1, int C1,
        const bf16* __restrict__ in2, int C2,
        const bf16* __restrict__ wp,
        const void* __restrict__ bias,
        const void* __restrict__ alpha,
        const float* __restrict__ flg,
        bf16* __restrict__ out,
        int H, int W, int Cout, int act) {
    const bool isb = (*flg != 0.f);
    const int Cin = C1 + C2;
    const int lane = threadIdx.x & 63;
    const int wave = threadIdx.x >> 6;
    const int quad = lane >> 4, l16 = lane & 15;
    const int cot = Cout >> 4;
    const int b = blockIdx.z / cot;
    const int co_base = (blockIdx.z % cot) << 4;
    const int r = (blockIdx.y << 2) + wave;
    const int c0 = blockIdx.x << 4;
    const int cog = co_base + l16;

    float bv = ldin(bias, cog, isb);
    f32x4 acc = {bv, bv, bv, bv};

    for (int ci0 = 0; ci0 < Cin; ci0 += 32) {
        const bool ext = (ci0 < C1);
        #pragma unroll
        for (int tap = 0; tap < 9; ++tap) {
            const int ih = r + tap / 3 - 1;
            const int iw = c0 + l16 + tap % 3 - 1;
            const bool ok = (ih >= 0) && (ih < H) && (iw >= 0) && (iw < W);
            short8 bfrag = *(const short8*)&wp[((size_t)tap * Cout + cog) * Cin + ci0 + quad * 8];
            short8 afrag = {0, 0, 0, 0, 0, 0, 0, 0};
            if (ext) {
                if (ok) {
                    size_t base = ((size_t)(b * C1 + ci0 + quad * 8)) * H * W + (size_t)ih * W + iw;
                    #pragma unroll
                    for (int j = 0; j < 8; ++j)
                        afrag[j] = f2bs(ldin(in1, base + (size_t)j * H * W, isb));
                }
            } else {
                if (ok)
                    afrag = *(const short8*)&in2[(((size_t)(b * H) + ih) * W + iw) * C2
                                                 + (ci0 - C1) + quad * 8];
            }
            acc = __builtin_amdgcn_mfma_f32_16x16x32_bf16(afrag, bfrag, acc, 0, 0, 0);
        }
    }

    float a = (act == 2) ? ldin(alpha, cog, isb) : 0.f;
    #pragma unroll
    for (int reg = 0; reg < 4; ++reg) {
        float v = acc[reg];
        if (act == 1) v = fmaxf(v, 0.f);
        else if (act == 2) v = (v >= 0.f) ? v : a * v;
        out[(((size_t)(b * H) + r) * W + c0 + (quad << 2) + reg) * Cout + cog] = f2b(v);
    }
}

// ---------------------------------------------------------------- fused CAUN tail, MFMA mask conv
// Block = one (b,c) x 64 pixels (4 waves x 16 px). Mask conv as GEMM:
// logits[j=36][px] = kw[36][K] . f[px][K]^T via mfma_f32_16x16x32_bf16:
//   A[m=l16 -> j-row][k] from LDS kw_s (48 rows: 36 real + 12 zero, K padded +8),
//   B[n=l16 -> pixel][k] = direct 16B global load from channels-last f,
//   D[row=quad*4+reg -> j][col=l16 -> pixel] -> LDS transpose -> epilogue threads
// remap to (pixel, g=(u,v)): one 9-way softmax + neighbor blend + scatter each.
// K in {16,32,64}; zero-padded to 32-chunks. HW divisible by 64 (holds here).
__global__ __launch_bounds__(256) void caun_mfma(
        const bf16* __restrict__ f,
        const void* __restrict__ xlow, int xext,
        const void* __restrict__ kw,
        const void* __restrict__ kb,
        const float* __restrict__ flg,
        bf16* __restrict__ out,
        int C, int K, int H, int W) {
    extern __shared__ char smraw[];
    const bool isb = (*flg != 0.f);
    const int KC = (K + 31) & ~31;
    const int KP = KC + 8;                       // +8 bf16 pad -> 2-way banks (free)
    bf16*  kw_s = (bf16*)smraw;                  // [48][KP]
    float* lg_s = (float*)(smraw + 48 * KP * 2); // [4 waves][48][17]

    const int bc = blockIdx.y;
    const int b = bc / C, c = bc % C;
    const int tid = threadIdx.x, wave = tid >> 6, lane = tid & 63;
    const int quad = lane >> 4, l16 = lane & 15;
    const int p0 = blockIdx.x << 6;

    // stage kw rows (j<36, k<K real; else zero)
    for (int i = tid; i < 48 * KC; i += 256) {
        int k = i % KC, j = i / KC;
        float v = (j < 36 && k < K) ? ldin(kw, (size_t)(c * 36 + j) * K + k, isb) : 0.f;
        kw_s[j * KP + k] = f2b(v);
    }
    __syncthreads();

    // MFMA: 16 pixels per wave, 3 j-tiles
    const int pw = p0 + (wave << 4);
    f32x4 acc[3] = {{0,0,0,0},{0,0,0,0},{0,0,0,0}};
    for (int kc = 0; kc < KC; kc += 32) {
        int kq = kc + quad * 8;
        short8 bfrag = {0,0,0,0,0,0,0,0};
        if (kq < K)
            bfrag = *(const short8*)&f[((size_t)b * H * W + pw + l16) * K + kq];
        #pragma unroll
        for (int t = 0; t < 3; ++t) {
            short8 afrag = *(const short8*)&kw_s[(t * 16 + l16) * KP + kq];
            acc[t] = __builtin_amdgcn_mfma_f32_16x16x32_bf16(afrag, bfrag, acc[t], 0, 0, 0);
        }
    }
    // D -> LDS transpose: row j_local = t*16+quad*4+reg, col pixel = l16
    float* ls = lg_s + wave * 48 * 17;
    #pragma unroll
    for (int t = 0; t < 3; ++t)
        #pragma unroll
        for (int reg = 0; reg < 4; ++reg)
            ls[(t * 16 + (quad << 2) + reg) * 17 + l16] = acc[t][reg];
    __syncthreads();

    // epilogue: thread = (pixel px_l of 64, g of 4)
    const int px_l = tid >> 2, g = tid & 3;
    const int p = p0 + px_l;
    const int h = p / W, w = p % W;
    const float* lp = lg_s + (px_l >> 4) * 48 * 17 + (px_l & 15);

    float lg[9];
    #pragma unroll
    for (int n = 0; n < 9; ++n)
        lg[n] = lp[(n * 4 + g) * 17] + ldin(kb, c * 36 + n * 4 + g, isb);

    float neigh[9];
    #pragma unroll
    for (int n = 0; n < 9; ++n) {
        int ih = h + n / 3 - 1; ih = min(max(ih, 0), H - 1);
        int iw = w + n % 3 - 1; iw = min(max(iw, 0), W - 1);
        neigh[n] = xext
            ? ldin(xlow, ((size_t)(b * C + c)) * H * W + (size_t)ih * W + iw, isb)
            : b2f(((const bf16*)xlow)[(((size_t)(b * H) + ih) * W + iw) * C + c]);
    }

    float mx = -1e30f;
    #pragma unroll
    for (int n = 0; n < 9; ++n) mx = fmaxf(mx, lg[n]);
    float se = 0.f, accv = 0.f;
    #pragma unroll
    for (int n = 0; n < 9; ++n) {
        float e = expf(lg[n] - mx);
        se += e;
        accv = fmaf(e, neigh[n], accv);
    }
    const int u = g >> 1, v = g & 1;
    size_t L = ((size_t)(w * 2 + v) * H + h) * 2 + u;    // torch permute(0,1,5,3,4,2)
    out[((size_t)b * 4 * H * W + L) * C + c] = f2b(accv / se);
}

// ---------------------------------------------------------------- memory bank: row-l2norm of mem
__global__ void memnorm_kernel(const void* __restrict__ mem, const float* __restrict__ flg,
                               float* __restrict__ mn) {
    bool isb = (*flg != 0.f);
    int s = threadIdx.x;          // 64 slots
    float v[32];
    float ss = 0.f;
    #pragma unroll
    for (int c = 0; c < 32; ++c) { v[c] = ldin(mem, s * 32 + c, isb); ss += v[c] * v[c]; }
    float inv = 1.f / fmaxf(sqrtf(ss), 1e-12f);
    #pragma unroll
    for (int c = 0; c < 32; ++c) mn[s * 32 + c] = v[c] * inv;
}

// ---------------------------------------------------------------- memory fusion (in place, channels-last bf16 ws)
__global__ __launch_bounds__(256, 2) void memfuse_kernel(
        bf16* __restrict__ x, const float* __restrict__ mn) {
    __shared__ float mns[64 * 32];
    for (int i = threadIdx.x; i < 64 * 32; i += blockDim.x) mns[i] = mn[i];
    __syncthreads();
    int idx = blockIdx.x * blockDim.x + threadIdx.x;   // over B*HW
    bf16* xp = x + (size_t)idx * 32;

    float feat[32];
    float ss = 0.f;
    #pragma unroll
    for (int c = 0; c < 32; ++c) { feat[c] = b2f(xp[c]); ss += feat[c] * feat[c]; }
    float inv = 1.f / fmaxf(sqrtf(ss), 1e-12f);

    float se = 0.f;
    float racc[32];
    #pragma unroll
    for (int c = 0; c < 32; ++c) racc[c] = 0.f;

    for (int s = 0; s < 64; ++s) {
        const float* mr = mns + s * 32;
        float dot = 0.f;
        #pragma unroll
        for (int c = 0; c < 32; ++c) dot = fmaf(feat[c], mr[c], dot);
        float e = expf(dot * inv);     // dot*inv in [-1,1] -> exp safe unshifted
        se += e;
        #pragma unroll
        for (int c = 0; c < 32; ++c) racc[c] = fmaf(e, mr[c], racc[c]);
    }
    float rse = 1.f / se;
    #pragma unroll
    for (int c = 0; c < 32; ++c)
        xp[c] = f2b(feat[c] + racc[c] * rse);
}

// ---------------------------------------------------------------- final 1x1 conv 32 -> 2 (x channels-last)
__global__ void final1x1_kernel(const bf16* __restrict__ x,
                                const void* __restrict__ fw, const void* __restrict__ fb,
                                const float* __restrict__ flg,
                                void* __restrict__ out, int HW) {
    bool isb = (*flg != 0.f);
    int idx = blockIdx.x * blockDim.x + threadIdx.x;   // over B*HW
    int b = idx / HW, p = idx % HW;
    const bf16* xp = x + (size_t)idx * 32;
    float a0 = ldin(fb, 0, isb), a1 = ldin(fb, 1, isb);
    #pragma unroll
    for (int c = 0; c < 32; ++c) {
        float v = b2f(xp[c]);
        a0 = fmaf(v, ldin(fw, c, isb), a0);
        a1 = fmaf(v, ldin(fw, 32 + c, isb), a1);
    }
    size_t i0 = (size_t)b * 2 * HW + p;
    size_t i1 = i0 + HW;
    if (isb) { ((bf16*)out)[i0] = f2b(a0); ((bf16*)out)[i1] = f2b(a1); }
    else     { ((float*)out)[i0] = a0;     ((float*)out)[i1] = a1; }
}

// ================================================================ host
extern "C" void kernel_launch(void* const* d_in, const int* in_sizes, int n_in,
                              void* d_out, int out_size, void* d_ws, size_t ws_size,
                              hipStream_t stream) {
    const void* x0_0 = d_in[0];
    const void* x1_0 = d_in[1];
    const void* x2_0 = d_in[2];
    const void* x3_0 = d_in[3];
    const void* c3_w1 = d_in[4];  const void* c3_b1 = d_in[5];  const void* c3_a1 = d_in[6];
    const void* c3_w2 = d_in[7];  const void* c3_b2 = d_in[8];  const void* c3_a2 = d_in[9];
    const void* c3_kw = d_in[10]; const void* c3_kb = d_in[11];
    const void* c2_w1 = d_in[12]; const void* c2_b1 = d_in[13]; const void* c2_a1 = d_in[14];
    const void* c2_w2 = d_in[15]; const void* c2_b2 = d_in[16]; const void* c2_a2 = d_in[17];
    const void* c2_kw = d_in[18]; const void* c2_kb = d_in[19];
    const void* c1_w1 = d_in[20]; const void* c1_b1 = d_in[21]; const void* c1_a1 = d_in[22];
    const void* c1_w2 = d_in[23]; const void* c1_b2 = d_in[24]; const void* c1_a2 = d_in[25];
    const void* c1_kw = d_in[26]; const void* c1_kb = d_in[27];
    const void* b21_w1 = d_in[28]; const void* b21_b1 = d_in[29];
    const void* b21_w2 = d_in[30]; const void* b21_b2 = d_in[31];
    const void* b12_w1 = d_in[32]; const void* b12_b1 = d_in[33];
    const void* b12_w2 = d_in[34]; const void* b12_b2 = d_in[35];
    const void* b03_w1 = d_in[36]; const void* b03_b1 = d_in[37];
    const void* b03_w2 = d_in[38]; const void* b03_b2 = d_in[39];
    const void* fin_w = d_in[40];  const void* fin_b = d_in[41];
    const void* memw  = d_in[42];
    (void)in_sizes; (void)n_in;

    const int TB = 256;
    auto blocks = [](int n) { return (n + 255) / 256; };

    const size_t NEED = 25165824 + 65536;
    if (ws_size < NEED) {
        diag_fill<<<blocks(out_size / 2), TB, 0, stream>>>(
            (unsigned int*)d_out, out_size / 2, (float)ws_size);
        return;
    }
    // tail (>= 65,280B): [0,55296) b03 weight slot, [55296,63488) mn, [63488,+4) flg
    size_t tail = (ws_size - 65536) & ~(size_t)255;
    bf16*  wtail = (bf16*)((char*)d_ws + tail);
    float* mn    = (float*)((char*)d_ws + tail + 55296);
    float* flg   = (float*)((char*)d_ws + tail + 63488);

    // 24 MiB arena (12,582,912 bf16 elems), channels-last, verified live ranges.
    bf16* A = (bf16*)d_ws;
    bf16* x3up  = A + 0;         // [2,64,64,256]
    bf16* ctx3p = A + 2097152;   // [2,32,32,128]
    bf16* f3a   = A + 2359296;   // [2,32,32,128]
    bf16* f3b   = A + 2621440;   // [2,32,32,64]
    bf16* t2a   = A + 2097152;   // [2,64,64,128]
    bf16* x2_1  = A + 0;         // [2,64,64,128]
    bf16* ctx2  = A + 1048576;   // [2,64,64,64]
    bf16* f2a   = A + 1572864;   // [2,64,64,64]
    bf16* f2b   = A + 2097152;   // [2,64,64,32]
    bf16* x2up  = A + 2359296;   // [2,128,128,128]
    bf16* t1a   = A + 0;         // [2,128,128,64]
    bf16* x1_2  = A + 10485760;  // [2,128,128,64]
    bf16* ctx1  = A + 4194304;   // [2,128,128,32]
    bf16* f1a   = A + 5242880;   // [2,128,128,32]
    bf16* f1b   = A + 9437184;   // [2,128,128,16]
    bf16* x1up  = A + 0;         // [2,256,256,64]
    bf16* t0a   = A + 8388608;   // [2,256,256,32]
    bf16* x0_3  = A + 0;         // [2,256,256,32]
    bf16* wslot = A + 6553600;   // 442,368 elems max (b21_w1)

    detect_kernel<<<1, 64, 0, stream>>>((const unsigned int*)x0_0, flg);

    auto cgrid = [](int H, int W, int Cout) { return dim3(W >> 4, H >> 2, 2 * (Cout >> 4)); };
    auto wpk = [&](const void* w, bf16* dst, int Cout, int Cin) {
        wpack_kernel<<<blocks(Cout * Cin * 9), TB, 0, stream>>>(w, flg, dst, Cout, Cin);
    };
    auto caun_shm = [](int K) {
        int KC = (K + 31) & ~31;
        return (size_t)(48 * (KC + 8) * 2 + 4 * 48 * 17 * 4);
    };

    // ---- caun3: ctx = pool(x2_0) -> [2,32,32,128] cl
    pool2_cl<<<blocks(262144), TB, 0, stream>>>(x2_0, flg, ctx3p, 2, 128, 32, 32);
    wpk(c3_w1, wslot, 128, 128);
    conv3x3_cl<<<cgrid(32, 32, 128), TB, 0, stream>>>(
        nullptr, 0, ctx3p, 128, wslot, c3_b1, c3_a1, flg, f3a, 32, 32, 128, 2);
    wpk(c3_w2, wslot, 64, 128);
    conv3x3_cl<<<cgrid(32, 32, 64), TB, 0, stream>>>(
        nullptr, 0, f3a, 128, wslot, c3_b2, c3_a2, flg, f3b, 32, 32, 64, 2);
    caun_mfma<<<dim3(16, 512), TB, caun_shm(64), stream>>>(
        f3b, x3_0, 1, c3_kw, c3_kb, flg, x3up, 256, 64, 32, 32);

    // ---- block21: cat(x2_0 ext[128], x3up cl[256]) -> 128 -> 128 @64x64
    wpk(b21_w1, wslot, 128, 384);
    conv3x3_cl<<<cgrid(64, 64, 128), TB, 0, stream>>>(
        x2_0, 128, x3up, 256, wslot, b21_b1, nullptr, flg, t2a, 64, 64, 128, 1);
    wpk(b21_w2, wslot, 128, 128);
    conv3x3_cl<<<cgrid(64, 64, 128), TB, 0, stream>>>(
        nullptr, 0, t2a, 128, wslot, b21_b2, nullptr, flg, x2_1, 64, 64, 128, 1);

    // ---- caun2: ctx = pool(x1_0) -> [2,64,64,64] cl
    pool2_cl<<<blocks(524288), TB, 0, stream>>>(x1_0, flg, ctx2, 2, 64, 64, 64);
    wpk(c2_w1, wslot, 64, 64);
    conv3x3_cl<<<cgrid(64, 64, 64), TB, 0, stream>>>(
        nullptr, 0, ctx2, 64, wslot, c2_b1, c2_a1, flg, f2a, 64, 64, 64, 2);
    wpk(c2_w2, wslot, 32, 64);
    conv3x3_cl<<<cgrid(64, 64, 32), TB, 0, stream>>>(
        nullptr, 0, f2a, 64, wslot, c2_b2, c2_a2, flg, f2b, 64, 64, 32, 2);
    caun_mfma<<<dim3(64, 256), TB, caun_shm(32), stream>>>(
        f2b, x2_1, 0, c2_kw, c2_kb, flg, x2up, 128, 32, 64, 64);

    // ---- block12: cat(x1_0 ext[64], x2up cl[128]) -> 64 -> 64 @128x128
    wpk(b12_w1, wslot, 64, 192);
    conv3x3_cl<<<cgrid(128, 128, 64), TB, 0, stream>>>(
        x1_0, 64, x2up, 128, wslot, b12_b1, nullptr, flg, t1a, 128, 128, 64, 1);
    wpk(b12_w2, wslot, 64, 64);
    conv3x3_cl<<<cgrid(128, 128, 64), TB, 0, stream>>>(
        nullptr, 0, t1a, 64, wslot, b12_b2, nullptr, flg, x1_2, 128, 128, 64, 1);

    // ---- caun1: ctx = pool(x0_0) -> [2,128,128,32] cl
    pool2_cl<<<blocks(1048576), TB, 0, stream>>>(x0_0, flg, ctx1, 2, 32, 128, 128);
    wpk(c1_w1, wslot, 32, 32);
    conv3x3_cl<<<cgrid(128, 128, 32), TB, 0, stream>>>(
        nullptr, 0, ctx1, 32, wslot, c1_b1, c1_a1, flg, f1a, 128, 128, 32, 2);
    wpk(c1_w2, wslot, 16, 32);
    conv3x3_cl<<<cgrid(128, 128, 16), TB, 0, stream>>>(
        nullptr, 0, f1a, 32, wslot, c1_b2, c1_a2, flg, f1b, 128, 128, 16, 2);
    caun_mfma<<<dim3(256, 128), TB, caun_shm(16), stream>>>(
        f1b, x1_2, 0, c1_kw, c1_kb, flg, x1up, 64, 16, 128, 128);

    // ---- block03: cat(x0_0 ext[32], x1up cl[64]) -> 32 -> 32 @256x256  (weights in tail slot)
    wpk(b03_w1, wtail, 32, 96);
    conv3x3_cl<<<cgrid(256, 256, 32), TB, 0, stream>>>(
        x0_0, 32, x1up, 64, wtail, b03_b1, nullptr, flg, t0a, 256, 256, 32, 1);
    wpk(b03_w2, wtail, 32, 32);
    conv3x3_cl<<<cgrid(256, 256, 32), TB, 0, stream>>>(
        nullptr, 0, t0a, 32, wtail, b03_b2, nullptr, flg, x0_3, 256, 256, 32, 1);

    // ---- memory-bank residual fusion (in place, cl) + final 1x1 conv -> [2,2,256,256]
    memnorm_kernel<<<1, 64, 0, stream>>>(memw, flg, mn);
    memfuse_kernel<<<512, TB, 0, stream>>>(x0_3, mn);
    final1x1_kernel<<<512, TB, 0, stream>>>(x0_3, fin_w, fin_b, flg, d_out, 256 * 256);
}

// Round 11
// 895.436 us; speedup vs baseline: 8.4374x; 1.1257x over previous
//
#include <hip/hip_runtime.h>
#include <hip/hip_bf16.h>
#include <math.h>

typedef __hip_bfloat16 bf16;
typedef short short8 __attribute__((ext_vector_type(8)));   // bf16x8 MFMA frag (4 VGPRs)
typedef float f32x4 __attribute__((ext_vector_type(4)));    // MFMA accumulator

static __device__ __forceinline__ float b2f(bf16 x) { return __bfloat162float(x); }
static __device__ __forceinline__ bf16  f2b(float x) { return __float2bfloat16(x); }
static __device__ __forceinline__ short f2bs(float x) { bf16 t = f2b(x); return *reinterpret_cast<short*>(&t); }

// Polymorphic input load: isb=true -> bf16 storage, else f32 storage.
static __device__ __forceinline__ float ldin(const void* p, size_t i, bool isb) {
    return isb ? b2f(((const bf16*)p)[i]) : ((const float*)p)[i];
}

// ---------------------------------------------------------------- dtype detect
__global__ void detect_kernel(const unsigned int* __restrict__ x, float* __restrict__ flagp) {
    __shared__ int sh[64];
    int insane = 0;
    for (int i = threadIdx.x; i < 1024; i += 64) {
        unsigned int lo = (x[i] & 0xFFFFu) << 16;
        float v = __uint_as_float(lo);
        if (!(fabsf(v) <= 1e6f)) insane++;
    }
    sh[threadIdx.x] = insane;
    __syncthreads();
    if (threadIdx.x == 0) {
        int t = 0;
        for (int i = 0; i < 64; ++i) t += sh[i];
        *flagp = (t < 16) ? 1.f : 0.f;            // 1 => inputs are bf16
    }
}

// ---------------------------------------------------------------- diagnostic fill
__global__ void diag_fill(unsigned int* __restrict__ out, int nwords, float val) {
    int i = blockIdx.x * blockDim.x + threadIdx.x;
    if (i < nwords) {
        unsigned short h = (unsigned short)(__float_as_uint(val) >> 16);
        out[i] = ((unsigned int)h << 16) | h;
    }
}

// ---------------------------------------------------------------- weight pack: [co][ci][tap] -> [tap][co][ci] bf16
__global__ void wpack_kernel(const void* __restrict__ wt, const float* __restrict__ flg,
                             bf16* __restrict__ dst, int Cout, int Cin) {
    bool isb = (*flg != 0.f);
    int n = Cout * Cin * 9;
    int idx = blockIdx.x * blockDim.x + threadIdx.x;
    if (idx >= n) return;
    int ci = idx % Cin;
    int co = (idx / Cin) % Cout;
    int tap = idx / (Cin * Cout);
    dst[idx] = f2b(ldin(wt, ((size_t)co * Cin + ci) * 9 + tap, isb));
}

// ---------------------------------------------------------------- NCHW ext -> channels-last bf16 (LDS tile transpose)
// Block: 32 channels x 64 pixels. grid = B * (C/32) * (HW/64).
__global__ void nchw2cl(const void* __restrict__ in, const float* __restrict__ flg,
                        bf16* __restrict__ out, int C, int HW) {
    __shared__ bf16 t[32][72];
    bool isb = (*flg != 0.f);
    int npx = HW >> 6, nc = C >> 5;
    int blk = blockIdx.x;
    int px0 = (blk % npx) << 6;
    int c0  = ((blk / npx) % nc) << 5;
    int b   = blk / (npx * nc);
    for (int i = threadIdx.x; i < 2048; i += 256) {
        int px = i & 63, c = i >> 6;       // consecutive tid -> consecutive px: coalesced read
        t[c][px] = f2b(ldin(in, ((size_t)(b * C + c0 + c)) * HW + px0 + px, isb));
    }
    __syncthreads();
    for (int i = threadIdx.x; i < 2048; i += 256) {
        int c = i & 31, px = i >> 5;       // consecutive tid -> consecutive c: coalesced write
        out[((size_t)b * HW + px0 + px) * C + c0 + c] = t[c][px];
    }
}

// ---------------------------------------------------------------- 2x2 mean pool: NCHW ext -> channels-last bf16 ws
__global__ void pool2_cl(const void* __restrict__ in, const float* __restrict__ flg,
                         bf16* __restrict__ out, int B, int C, int H2, int W2) {
    bool isb = (*flg != 0.f);
    int idx = blockIdx.x * blockDim.x + threadIdx.x;
    int total = B * H2 * W2 * C;
    if (idx >= total) return;
    int c = idx % C;
    int pix = idx / C;
    int w = pix % W2;
    int h = (pix / W2) % H2;
    int b = pix / (W2 * H2);
    int H = H2 * 2, W = W2 * 2;
    size_t base = ((size_t)(b * C + c)) * H * W;
    float s = ldin(in, base + (size_t)(2*h)*W + 2*w, isb)   + ldin(in, base + (size_t)(2*h)*W + 2*w + 1, isb)
            + ldin(in, base + (size_t)(2*h+1)*W + 2*w, isb) + ldin(in, base + (size_t)(2*h+1)*W + 2*w + 1, isb);
    out[idx] = f2b(0.25f * s);
}

// ---------------------------------------------------------------- MFMA conv3x3, channels-last, no LDS
// Wave = RT row-segments of 16 px x 16 co -> RT independent MFMA chains (ILP).
// Per tap: 1 B-frag + RT A-frags + RT MFMAs. in1: first C1 channels, ext1=1 ->
// external NCHW (dtype flag, 8 scalar loads/frag), else channels-last bf16.
// in2: channels-last bf16. wp packed [tap][Cout][Cin].
// grid = (W/16, H/(4*RT), B * Cout/16). C1, C2 multiples of 32 (or 0).
// Fragments (HW-verified): A[m=l16 -> pixel][k=quad*8+j], B[n=l16 -> co][k],
// D[col=l16 -> co][row=quad*4+reg -> pixel].
template<int RT>
__global__ __launch_bounds__(256) void conv3x3_cl(
        const void* __restrict__ in1, int C1, int ext1,
        const bf16* __restrict__ in2, int C2,
        const bf16* __restrict__ wp,
        const void* __restrict__ bias,
        const void* __restrict__ alpha,
        const float* __restrict__ flg,
        bf16* __restrict__ out,
        int H, int W, int Cout, int act) {
    const bool isb = (*flg != 0.f);
    const int Cin = C1 + C2;
    const int lane = threadIdx.x & 63;
    const int wave = threadIdx.x >> 6;
    const int quad = lane >> 4, l16 = lane & 15;
    const int cot = Cout >> 4;
    const int b = blockIdx.z / cot;
    const int co_base = (blockIdx.z % cot) << 4;
    const int r0 = (blockIdx.y * 4 + wave) * RT;      // wave's first output row
    const int c0 = blockIdx.x << 4;
    const int cog = co_base + l16;

    float bv = ldin(bias, cog, isb);
    f32x4 acc[RT];
    #pragma unroll
    for (int t = 0; t < RT; ++t) acc[t] = {bv, bv, bv, bv};

    for (int ci0 = 0; ci0 < Cin; ci0 += 32) {
        const bool from1 = (ci0 < C1);
        #pragma unroll
        for (int tap = 0; tap < 9; ++tap) {
            const int kh = tap / 3, kw = tap % 3;
            const int iw = c0 + l16 + kw - 1;
            const bool okc = (iw >= 0) && (iw < W);
            short8 bfrag = *(const short8*)&wp[((size_t)tap * Cout + cog) * Cin + ci0 + quad * 8];
            short8 af[RT];
            #pragma unroll
            for (int t = 0; t < RT; ++t) {
                const int ih = r0 + t + kh - 1;
                const bool ok = okc && (ih >= 0) && (ih < H);
                af[t] = short8{0, 0, 0, 0, 0, 0, 0, 0};
                if (from1) {
                    if (ext1) {
                        if (ok) {
                            size_t base = ((size_t)(b * C1 + ci0 + quad * 8)) * H * W
                                        + (size_t)ih * W + iw;
                            #pragma unroll
                            for (int j = 0; j < 8; ++j)
                                af[t][j] = f2bs(ldin(in1, base + (size_t)j * H * W, isb));
                        }
                    } else {
                        if (ok)
                            af[t] = *(const short8*)&((const bf16*)in1)[
                                (((size_t)(b * H) + ih) * W + iw) * C1 + ci0 + quad * 8];
                    }
                } else {
                    if (ok)
                        af[t] = *(const short8*)&in2[(((size_t)(b * H) + ih) * W + iw) * C2
                                                     + (ci0 - C1) + quad * 8];
                }
            }
            #pragma unroll
            for (int t = 0; t < RT; ++t)
                acc[t] = __builtin_amdgcn_mfma_f32_16x16x32_bf16(af[t], bfrag, acc[t], 0, 0, 0);
        }
    }

    float a = (act == 2) ? ldin(alpha, cog, isb) : 0.f;
    #pragma unroll
    for (int t = 0; t < RT; ++t) {
        #pragma unroll
        for (int reg = 0; reg < 4; ++reg) {
            float v = acc[t][reg];
            if (act == 1) v = fmaxf(v, 0.f);
            else if (act == 2) v = (v >= 0.f) ? v : a * v;
            out[(((size_t)(b * H) + r0 + t) * W + c0 + (quad << 2) + reg) * Cout + cog] = f2b(v);
        }
    }
}

// ---------------------------------------------------------------- fused CAUN tail, MFMA mask conv
__global__ __launch_bounds__(256) void caun_mfma(
        const bf16* __restrict__ f,
        const void* __restrict__ xlow, int xext,
        const void* __restrict__ kw,
        const void* __restrict__ kb,
        const float* __restrict__ flg,
        bf16* __restrict__ out,
        int C, int K, int H, int W) {
    extern __shared__ char smraw[];
    const bool isb = (*flg != 0.f);
    const int KC = (K + 31) & ~31;
    const int KP = KC + 8;                       // +8 bf16 pad -> 2-way banks (free)
    bf16*  kw_s = (bf16*)smraw;                  // [48][KP]
    float* lg_s = (float*)(smraw + 48 * KP * 2); // [4 waves][48][17]

    const int bc = blockIdx.y;
    const int b = bc / C, c = bc % C;
    const int tid = threadIdx.x, wave = tid >> 6, lane = tid & 63;
    const int quad = lane >> 4, l16 = lane & 15;
    const int p0 = blockIdx.x << 6;

    for (int i = tid; i < 48 * KC; i += 256) {
        int k = i % KC, j = i / KC;
        float v = (j < 36 && k < K) ? ldin(kw, (size_t)(c * 36 + j) * K + k, isb) : 0.f;
        kw_s[j * KP + k] = f2b(v);
    }
    __syncthreads();

    const int pw = p0 + (wave << 4);
    f32x4 acc[3] = {{0,0,0,0},{0,0,0,0},{0,0,0,0}};
    for (int kc = 0; kc < KC; kc += 32) {
        int kq = kc + quad * 8;
        short8 bfrag = {0,0,0,0,0,0,0,0};
        if (kq < K)
            bfrag = *(const short8*)&f[((size_t)b * H * W + pw + l16) * K + kq];
        #pragma unroll
        for (int t = 0; t < 3; ++t) {
            short8 afrag = *(const short8*)&kw_s[(t * 16 + l16) * KP + kq];
            acc[t] = __builtin_amdgcn_mfma_f32_16x16x32_bf16(afrag, bfrag, acc[t], 0, 0, 0);
        }
    }
    float* ls = lg_s + wave * 48 * 17;
    #pragma unroll
    for (int t = 0; t < 3; ++t)
        #pragma unroll
        for (int reg = 0; reg < 4; ++reg)
            ls[(t * 16 + (quad << 2) + reg) * 17 + l16] = acc[t][reg];
    __syncthreads();

    const int px_l = tid >> 2, g = tid & 3;
    const int p = p0 + px_l;
    const int h = p / W, w = p % W;
    const float* lp = lg_s + (px_l >> 4) * 48 * 17 + (px_l & 15);

    float lg[9];
    #pragma unroll
    for (int n = 0; n < 9; ++n)
        lg[n] = lp[(n * 4 + g) * 17] + ldin(kb, c * 36 + n * 4 + g, isb);

    float neigh[9];
    #pragma unroll
    for (int n = 0; n < 9; ++n) {
        int ih = h + n / 3 - 1; ih = min(max(ih, 0), H - 1);
        int iw = w + n % 3 - 1; iw = min(max(iw, 0), W - 1);
        neigh[n] = xext
            ? ldin(xlow, ((size_t)(b * C + c)) * H * W + (size_t)ih * W + iw, isb)
            : b2f(((const bf16*)xlow)[(((size_t)(b * H) + ih) * W + iw) * C + c]);
    }

    float mx = -1e30f;
    #pragma unroll
    for (int n = 0; n < 9; ++n) mx = fmaxf(mx, lg[n]);
    float se = 0.f, accv = 0.f;
    #pragma unroll
    for (int n = 0; n < 9; ++n) {
        float e = expf(lg[n] - mx);
        se += e;
        accv = fmaf(e, neigh[n], accv);
    }
    const int u = g >> 1, v = g & 1;
    size_t L = ((size_t)(w * 2 + v) * H + h) * 2 + u;    // torch permute(0,1,5,3,4,2)
    out[((size_t)b * 4 * H * W + L) * C + c] = f2b(accv / se);
}

// ---------------------------------------------------------------- memory bank: row-l2norm of mem
__global__ void memnorm_kernel(const void* __restrict__ mem, const float* __restrict__ flg,
                               float* __restrict__ mn) {
    bool isb = (*flg != 0.f);
    int s = threadIdx.x;          // 64 slots
    float v[32];
    float ss = 0.f;
    #pragma unroll
    for (int c = 0; c < 32; ++c) { v[c] = ldin(mem, s * 32 + c, isb); ss += v[c] * v[c]; }
    float inv = 1.f / fmaxf(sqrtf(ss), 1e-12f);
    #pragma unroll
    for (int c = 0; c < 32; ++c) mn[s * 32 + c] = v[c] * inv;
}

// ---------------------------------------------------------------- memory fusion (in place, channels-last bf16 ws)
__global__ __launch_bounds__(256, 2) void memfuse_kernel(
        bf16* __restrict__ x, const float* __restrict__ mn) {
    __shared__ float mns[64 * 32];
    for (int i = threadIdx.x; i < 64 * 32; i += blockDim.x) mns[i] = mn[i];
    __syncthreads();
    int idx = blockIdx.x * blockDim.x + threadIdx.x;   // over B*HW
    bf16* xp = x + (size_t)idx * 32;

    float feat[32];
    float ss = 0.f;
    #pragma unroll
    for (int c = 0; c < 32; ++c) { feat[c] = b2f(xp[c]); ss += feat[c] * feat[c]; }
    float inv = 1.f / fmaxf(sqrtf(ss), 1e-12f);

    float se = 0.f;
    float racc[32];
    #pragma unroll
    for (int c = 0; c < 32; ++c) racc[c] = 0.f;

    for (int s = 0; s < 64; ++s) {
        const float* mr = mns + s * 32;
        float dot = 0.f;
        #pragma unroll
        for (int c = 0; c < 32; ++c) dot = fmaf(feat[c], mr[c], dot);
        float e = expf(dot * inv);     // dot*inv in [-1,1] -> exp safe unshifted
        se += e;
        #pragma unroll
        for (int c = 0; c < 32; ++c) racc[c] = fmaf(e, mr[c], racc[c]);
    }
    float rse = 1.f / se;
    #pragma unroll
    for (int c = 0; c < 32; ++c)
        xp[c] = f2b(feat[c] + racc[c] * rse);
}

// ---------------------------------------------------------------- final 1x1 conv 32 -> 2 (x channels-last)
__global__ void final1x1_kernel(const bf16* __restrict__ x,
                                const void* __restrict__ fw, const void* __restrict__ fb,
                                const float* __restrict__ flg,
                                void* __restrict__ out, int HW) {
    bool isb = (*flg != 0.f);
    int idx = blockIdx.x * blockDim.x + threadIdx.x;   // over B*HW
    int b = idx / HW, p = idx % HW;
    const bf16* xp = x + (size_t)idx * 32;
    float a0 = ldin(fb, 0, isb), a1 = ldin(fb, 1, isb);
    #pragma unroll
    for (int c = 0; c < 32; ++c) {
        float v = b2f(xp[c]);
        a0 = fmaf(v, ldin(fw, c, isb), a0);
        a1 = fmaf(v, ldin(fw, 32 + c, isb), a1);
    }
    size_t i0 = (size_t)b * 2 * HW + p;
    size_t i1 = i0 + HW;
    if (isb) { ((bf16*)out)[i0] = f2b(a0); ((bf16*)out)[i1] = f2b(a1); }
    else     { ((float*)out)[i0] = a0;     ((float*)out)[i1] = a1; }
}

// ================================================================ host
extern "C" void kernel_launch(void* const* d_in, const int* in_sizes, int n_in,
                              void* d_out, int out_size, void* d_ws, size_t ws_size,
                              hipStream_t stream) {
    const void* x0_0 = d_in[0];
    const void* x1_0 = d_in[1];
    const void* x2_0 = d_in[2];
    const void* x3_0 = d_in[3];
    const void* c3_w1 = d_in[4];  const void* c3_b1 = d_in[5];  const void* c3_a1 = d_in[6];
    const void* c3_w2 = d_in[7];  const void* c3_b2 = d_in[8];  const void* c3_a2 = d_in[9];
    const void* c3_kw = d_in[10]; const void* c3_kb = d_in[11];
    const void* c2_w1 = d_in[12]; const void* c2_b1 = d_in[13]; const void* c2_a1 = d_in[14];
    const void* c2_w2 = d_in[15]; const void* c2_b2 = d_in[16]; const void* c2_a2 = d_in[17];
    const void* c2_kw = d_in[18]; const void* c2_kb = d_in[19];
    const void* c1_w1 = d_in[20]; const void* c1_b1 = d_in[21]; const void* c1_a1 = d_in[22];
    const void* c1_w2 = d_in[23]; const void* c1_b2 = d_in[24]; const void* c1_a2 = d_in[25];
    const void* c1_kw = d_in[26]; const void* c1_kb = d_in[27];
    const void* b21_w1 = d_in[28]; const void* b21_b1 = d_in[29];
    const void* b21_w2 = d_in[30]; const void* b21_b2 = d_in[31];
    const void* b12_w1 = d_in[32]; const void* b12_b1 = d_in[33];
    const void* b12_w2 = d_in[34]; const void* b12_b2 = d_in[35];
    const void* b03_w1 = d_in[36]; const void* b03_b1 = d_in[37];
    const void* b03_w2 = d_in[38]; const void* b03_b2 = d_in[39];
    const void* fin_w = d_in[40];  const void* fin_b = d_in[41];
    const void* memw  = d_in[42];
    (void)in_sizes; (void)n_in;

    const int TB = 256;
    auto blocks = [](int n) { return (n + 255) / 256; };

    const size_t NEED = 25165824 + 65536;
    if (ws_size < NEED) {
        diag_fill<<<blocks(out_size / 2), TB, 0, stream>>>(
            (unsigned int*)d_out, out_size / 2, (float)ws_size);
        return;
    }
    // tail (>= 65,280B): [0,55296) b03 weight slot, [55296,63488) mn, [63488,+4) flg
    size_t tail = (ws_size - 65536) & ~(size_t)255;
    bf16*  wtail = (bf16*)((char*)d_ws + tail);
    float* mn    = (float*)((char*)d_ws + tail + 55296);
    float* flg   = (float*)((char*)d_ws + tail + 63488);

    // 24 MiB arena (12,582,912 bf16 elems), channels-last, verified live ranges.
    bf16* A = (bf16*)d_ws;
    bf16* x3up  = A + 0;         // [2,64,64,256]
    bf16* ctx3p = A + 2097152;   // [2,32,32,128]
    bf16* f3a   = A + 2359296;   // [2,32,32,128]
    bf16* f3b   = A + 2621440;   // [2,32,32,64]
    bf16* t2a   = A + 2097152;   // [2,64,64,128]
    bf16* x2cl  = A + 3145728;   // [2,64,64,128] cl copy of x2_0 (live: ->b21c1)
    bf16* x2_1  = A + 0;         // [2,64,64,128]
    bf16* ctx2  = A + 1048576;   // [2,64,64,64]
    bf16* f2a   = A + 1572864;   // [2,64,64,64]
    bf16* f2b   = A + 2097152;   // [2,64,64,32]
    bf16* x2up  = A + 2359296;   // [2,128,128,128]
    bf16* t1a   = A + 0;         // [2,128,128,64]
    bf16* x1cl  = A + 6995968;   // [2,128,128,64] cl copy of x1_0 (live: ->b12c1)
    bf16* x1_2  = A + 10485760;  // [2,128,128,64]
    bf16* ctx1  = A + 4194304;   // [2,128,128,32]
    bf16* f1a   = A + 5242880;   // [2,128,128,32]
    bf16* f1b   = A + 9437184;   // [2,128,128,16]
    bf16* x1up  = A + 0;         // [2,256,256,64]
    bf16* t0a   = A + 8388608;   // [2,256,256,32]
    bf16* x0_3  = A + 0;         // [2,256,256,32]
    bf16* wslot = A + 6553600;   // 442,368 elems max (b21_w1)

    detect_kernel<<<1, 64, 0, stream>>>((const unsigned int*)x0_0, flg);

    auto wpk = [&](const void* w, bf16* dst, int Cout, int Cin) {
        wpack_kernel<<<blocks(Cout * Cin * 9), TB, 0, stream>>>(w, flg, dst, Cout, Cin);
    };
    auto caun_shm = [](int K) {
        int KC = (K + 31) & ~31;
        return (size_t)(48 * (KC + 8) * 2 + 4 * 48 * 17 * 4);
    };
    auto cg = [](int H, int W, int Cout, int RT) {
        return dim3(W >> 4, H / (4 * RT), 2 * (Cout >> 4));
    };

    // ---- caun3: ctx = pool(x2_0) -> [2,32,32,128] cl
    pool2_cl<<<blocks(262144), TB, 0, stream>>>(x2_0, flg, ctx3p, 2, 128, 32, 32);
    wpk(c3_w1, wslot, 128, 128);
    conv3x3_cl<1><<<cg(32, 32, 128, 1), TB, 0, stream>>>(
        nullptr, 0, 0, ctx3p, 128, wslot, c3_b1, c3_a1, flg, f3a, 32, 32, 128, 2);
    wpk(c3_w2, wslot, 64, 128);
    conv3x3_cl<1><<<cg(32, 32, 64, 1), TB, 0, stream>>>(
        nullptr, 0, 0, f3a, 128, wslot, c3_b2, c3_a2, flg, f3b, 32, 32, 64, 2);
    caun_mfma<<<dim3(16, 512), TB, caun_shm(64), stream>>>(
        f3b, x3_0, 1, c3_kw, c3_kb, flg, x3up, 256, 64, 32, 32);

    // ---- block21: cat(x2_0 -> cl [128], x3up cl[256]) -> 128 -> 128 @64x64
    nchw2cl<<<2 * 4 * 64, TB, 0, stream>>>(x2_0, flg, x2cl, 128, 4096);
    wpk(b21_w1, wslot, 128, 384);
    conv3x3_cl<2><<<cg(64, 64, 128, 2), TB, 0, stream>>>(
        x2cl, 128, 0, x3up, 256, wslot, b21_b1, nullptr, flg, t2a, 64, 64, 128, 1);
    wpk(b21_w2, wslot, 128, 128);
    conv3x3_cl<2><<<cg(64, 64, 128, 2), TB, 0, stream>>>(
        nullptr, 0, 0, t2a, 128, wslot, b21_b2, nullptr, flg, x2_1, 64, 64, 128, 1);

    // ---- caun2: ctx = pool(x1_0) -> [2,64,64,64] cl
    pool2_cl<<<blocks(524288), TB, 0, stream>>>(x1_0, flg, ctx2, 2, 64, 64, 64);
    wpk(c2_w1, wslot, 64, 64);
    conv3x3_cl<2><<<cg(64, 64, 64, 2), TB, 0, stream>>>(
        nullptr, 0, 0, ctx2, 64, wslot, c2_b1, c2_a1, flg, f2a, 64, 64, 64, 2);
    wpk(c2_w2, wslot, 32, 64);
    conv3x3_cl<1><<<cg(64, 64, 32, 1), TB, 0, stream>>>(
        nullptr, 0, 0, f2a, 64, wslot, c2_b2, c2_a2, flg, f2b, 64, 64, 32, 2);
    caun_mfma<<<dim3(64, 256), TB, caun_shm(32), stream>>>(
        f2b, x2_1, 0, c2_kw, c2_kb, flg, x2up, 128, 32, 64, 64);

    // ---- block12: cat(x1_0 -> cl [64], x2up cl[128]) -> 64 -> 64 @128x128
    nchw2cl<<<2 * 2 * 256, TB, 0, stream>>>(x1_0, flg, x1cl, 64, 16384);
    wpk(b12_w1, wslot, 64, 192);
    conv3x3_cl<4><<<cg(128, 128, 64, 4), TB, 0, stream>>>(
        x1cl, 64, 0, x2up, 128, wslot, b12_b1, nullptr, flg, t1a, 128, 128, 64, 1);
    wpk(b12_w2, wslot, 64, 64);
    conv3x3_cl<4><<<cg(128, 128, 64, 4), TB, 0, stream>>>(
        nullptr, 0, 0, t1a, 64, wslot, b12_b2, nullptr, flg, x1_2, 128, 128, 64, 1);

    // ---- caun1: ctx = pool(x0_0) -> [2,128,128,32] cl
    pool2_cl<<<blocks(1048576), TB, 0, stream>>>(x0_0, flg, ctx1, 2, 32, 128, 128);
    wpk(c1_w1, wslot, 32, 32);
    conv3x3_cl<2><<<cg(128, 128, 32, 2), TB, 0, stream>>>(
        nullptr, 0, 0, ctx1, 32, wslot, c1_b1, c1_a1, flg, f1a, 128, 128, 32, 2);
    wpk(c1_w2, wslot, 16, 32);
    conv3x3_cl<2><<<cg(128, 128, 16, 2), TB, 0, stream>>>(
        nullptr, 0, 0, f1a, 32, wslot, c1_b2, c1_a2, flg, f1b, 128, 128, 16, 2);
    caun_mfma<<<dim3(256, 128), TB, caun_shm(16), stream>>>(
        f1b, x1_2, 0, c1_kw, c1_kb, flg, x1up, 64, 16, 128, 128);

    // ---- block03: cat(x0_0 ext[32], x1up cl[64]) -> 32 -> 32 @256x256  (weights in tail slot)
    wpk(b03_w1, wtail, 32, 96);
    conv3x3_cl<4><<<cg(256, 256, 32, 4), TB, 0, stream>>>(
        x0_0, 32, 1, x1up, 64, wtail, b03_b1, nullptr, flg, t0a, 256, 256, 32, 1);
    wpk(b03_w2, wtail, 32, 32);
    conv3x3_cl<4><<<cg(256, 256, 32, 4), TB, 0, stream>>>(
        nullptr, 0, 0, t0a, 32, wtail, b03_b2, nullptr, flg, x0_3, 256, 256, 32, 1);

    // ---- memory-bank residual fusion (in place, cl) + final 1x1 conv -> [2,2,256,256]
    memnorm_kernel<<<1, 64, 0, stream>>>(memw, flg, mn);
    memfuse_kernel<<<512, TB, 0, stream>>>(x0_3, mn);
    final1x1_kernel<<<512, TB, 0, stream>>>(x0_3, fin_w, fin_b, flg, d_out, 256 * 256);
}

// Round 12
// 751.747 us; speedup vs baseline: 10.0501x; 1.1911x over previous
//
#include <hip/hip_runtime.h>
#include <hip/hip_bf16.h>
#include <math.h>

typedef __hip_bfloat16 bf16;
typedef short short8 __attribute__((ext_vector_type(8)));   // bf16x8 MFMA frag (4 VGPRs)
typedef float f32x4 __attribute__((ext_vector_type(4)));    // MFMA accumulator

static __device__ __forceinline__ float b2f(bf16 x) { return __bfloat162float(x); }
static __device__ __forceinline__ bf16  f2b(float x) { return __float2bfloat16(x); }
static __device__ __forceinline__ short f2bs(float x) { bf16 t = f2b(x); return *reinterpret_cast<short*>(&t); }

// Polymorphic input load: isb=true -> bf16 storage, else f32 storage.
static __device__ __forceinline__ float ldin(const void* p, size_t i, bool isb) {
    return isb ? b2f(((const bf16*)p)[i]) : ((const float*)p)[i];
}

// ---------------------------------------------------------------- dtype detect
__global__ void detect_kernel(const unsigned int* __restrict__ x, float* __restrict__ flagp) {
    __shared__ int sh[64];
    int insane = 0;
    for (int i = threadIdx.x; i < 1024; i += 64) {
        unsigned int lo = (x[i] & 0xFFFFu) << 16;
        float v = __uint_as_float(lo);
        if (!(fabsf(v) <= 1e6f)) insane++;
    }
    sh[threadIdx.x] = insane;
    __syncthreads();
    if (threadIdx.x == 0) {
        int t = 0;
        for (int i = 0; i < 64; ++i) t += sh[i];
        *flagp = (t < 16) ? 1.f : 0.f;            // 1 => inputs are bf16
    }
}

// ---------------------------------------------------------------- diagnostic fill
__global__ void diag_fill(unsigned int* __restrict__ out, int nwords, float val) {
    int i = blockIdx.x * blockDim.x + threadIdx.x;
    if (i < nwords) {
        unsigned short h = (unsigned short)(__float_as_uint(val) >> 16);
        out[i] = ((unsigned int)h << 16) | h;
    }
}

// ---------------------------------------------------------------- weight pack: [co][ci][tap] -> [tap][co][ci] bf16
__global__ void wpack_kernel(const void* __restrict__ wt, const float* __restrict__ flg,
                             bf16* __restrict__ dst, int Cout, int Cin) {
    bool isb = (*flg != 0.f);
    int n = Cout * Cin * 9;
    int idx = blockIdx.x * blockDim.x + threadIdx.x;
    if (idx >= n) return;
    int ci = idx % Cin;
    int co = (idx / Cin) % Cout;
    int tap = idx / (Cin * Cout);
    dst[idx] = f2b(ldin(wt, ((size_t)co * Cin + ci) * 9 + tap, isb));
}

// ---------------------------------------------------------------- NCHW ext -> channels-last bf16 (LDS tile transpose)
// Block: 32 channels x 64 pixels. grid = B * (C/32) * (HW/64).
__global__ void nchw2cl(const void* __restrict__ in, const float* __restrict__ flg,
                        bf16* __restrict__ out, int C, int HW) {
    __shared__ bf16 t[32][72];
    bool isb = (*flg != 0.f);
    int npx = HW >> 6, nc = C >> 5;
    int blk = blockIdx.x;
    int px0 = (blk % npx) << 6;
    int c0  = ((blk / npx) % nc) << 5;
    int b   = blk / (npx * nc);
    for (int i = threadIdx.x; i < 2048; i += 256) {
        int px = i & 63, c = i >> 6;       // consecutive tid -> consecutive px: coalesced read
        t[c][px] = f2b(ldin(in, ((size_t)(b * C + c0 + c)) * HW + px0 + px, isb));
    }
    __syncthreads();
    for (int i = threadIdx.x; i < 2048; i += 256) {
        int c = i & 31, px = i >> 5;       // consecutive tid -> consecutive c: coalesced write
        out[((size_t)b * HW + px0 + px) * C + c0 + c] = t[c][px];
    }
}

// ---------------------------------------------------------------- 2x2 mean pool: NCHW ext -> channels-last bf16 ws
__global__ void pool2_cl(const void* __restrict__ in, const float* __restrict__ flg,
                         bf16* __restrict__ out, int B, int C, int H2, int W2) {
    bool isb = (*flg != 0.f);
    int idx = blockIdx.x * blockDim.x + threadIdx.x;
    int total = B * H2 * W2 * C;
    if (idx >= total) return;
    int c = idx % C;
    int pix = idx / C;
    int w = pix % W2;
    int h = (pix / W2) % H2;
    int b = pix / (W2 * H2);
    int H = H2 * 2, W = W2 * 2;
    size_t base = ((size_t)(b * C + c)) * H * W;
    float s = ldin(in, base + (size_t)(2*h)*W + 2*w, isb)   + ldin(in, base + (size_t)(2*h)*W + 2*w + 1, isb)
            + ldin(in, base + (size_t)(2*h+1)*W + 2*w, isb) + ldin(in, base + (size_t)(2*h+1)*W + 2*w + 1, isb);
    out[idx] = f2b(0.25f * s);
}

// ---------------------------------------------------------------- MFMA conv3x3, channels-last, no LDS
// Wave = RT row-segments of 16 px x 16 co. kw-outer loop: per (chunk, kw) load
// RT+2 shared row frags once, then 3 B-frags x RT MFMAs (acc[t] += F[t+kh]*B(kh,kw)).
// Halves A-frag loads vs tap-ordered (18 vs 36 per chunk at RT=4) and batches
// independent loads ahead of the MFMA burst. in1: first C1 channels, ext1=1 ->
// external NCHW (dtype flag, scalar assembly), else channels-last bf16.
// grid = (W/16, H/(4*RT), B * Cout/16). C1, C2 multiples of 32 (or 0).
// Fragments (HW-verified): A[m=l16 -> pixel][k=quad*8+j], B[n=l16 -> co][k],
// D[col=l16 -> co][row=quad*4+reg -> pixel].
template<int RT>
__global__ __launch_bounds__(256) void conv3x3_cl(
        const void* __restrict__ in1, int C1, int ext1,
        const bf16* __restrict__ in2, int C2,
        const bf16* __restrict__ wp,
        const void* __restrict__ bias,
        const void* __restrict__ alpha,
        const float* __restrict__ flg,
        bf16* __restrict__ out,
        int H, int W, int Cout, int act) {
    const bool isb = (*flg != 0.f);
    const int Cin = C1 + C2;
    const int lane = threadIdx.x & 63;
    const int wave = threadIdx.x >> 6;
    const int quad = lane >> 4, l16 = lane & 15;
    const int cot = Cout >> 4;
    const int b = blockIdx.z / cot;
    const int co_base = (blockIdx.z % cot) << 4;
    const int r0 = (blockIdx.y * 4 + wave) * RT;      // wave's first output row
    const int c0 = blockIdx.x << 4;
    const int cog = co_base + l16;

    float bv = ldin(bias, cog, isb);
    f32x4 acc[RT];
    #pragma unroll
    for (int t = 0; t < RT; ++t) acc[t] = {bv, bv, bv, bv};

    for (int ci0 = 0; ci0 < Cin; ci0 += 32) {
        const bool from1 = (ci0 < C1);
        #pragma unroll
        for (int kw = 0; kw < 3; ++kw) {
            const int iw = c0 + l16 + kw - 1;
            const bool okc = (iw >= 0) && (iw < W);
            // shared row frags F[j] = input row r0 + j - 1, j = 0..RT+1
            short8 F[RT + 2];
            #pragma unroll
            for (int j = 0; j < RT + 2; ++j) {
                const int ih = r0 + j - 1;
                const bool ok = okc && (ih >= 0) && (ih < H);
                F[j] = short8{0, 0, 0, 0, 0, 0, 0, 0};
                if (from1) {
                    if (ext1) {
                        if (ok) {
                            size_t base = ((size_t)(b * C1 + ci0 + quad * 8)) * H * W
                                        + (size_t)ih * W + iw;
                            #pragma unroll
                            for (int jj = 0; jj < 8; ++jj)
                                F[j][jj] = f2bs(ldin(in1, base + (size_t)jj * H * W, isb));
                        }
                    } else {
                        if (ok)
                            F[j] = *(const short8*)&((const bf16*)in1)[
                                (((size_t)(b * H) + ih) * W + iw) * C1 + ci0 + quad * 8];
                    }
                } else {
                    if (ok)
                        F[j] = *(const short8*)&in2[(((size_t)(b * H) + ih) * W + iw) * C2
                                                     + (ci0 - C1) + quad * 8];
                }
            }
            #pragma unroll
            for (int kh = 0; kh < 3; ++kh) {
                short8 bfrag = *(const short8*)&wp[((size_t)(kh * 3 + kw) * Cout + cog) * Cin
                                                   + ci0 + quad * 8];
                #pragma unroll
                for (int t = 0; t < RT; ++t)
                    acc[t] = __builtin_amdgcn_mfma_f32_16x16x32_bf16(F[t + kh], bfrag, acc[t], 0, 0, 0);
            }
        }
    }

    float a = (act == 2) ? ldin(alpha, cog, isb) : 0.f;
    #pragma unroll
    for (int t = 0; t < RT; ++t) {
        #pragma unroll
        for (int reg = 0; reg < 4; ++reg) {
            float v = acc[t][reg];
            if (act == 1) v = fmaxf(v, 0.f);
            else if (act == 2) v = (v >= 0.f) ? v : a * v;
            out[(((size_t)(b * H) + r0 + t) * W + c0 + (quad << 2) + reg) * Cout + cog] = f2b(v);
        }
    }
}

// ---------------------------------------------------------------- fused CAUN tail, MFMA mask conv
__global__ __launch_bounds__(256) void caun_mfma(
        const bf16* __restrict__ f,
        const void* __restrict__ xlow, int xext,
        const void* __restrict__ kw,
        const void* __restrict__ kb,
        const float* __restrict__ flg,
        bf16* __restrict__ out,
        int C, int K, int H, int W) {
    extern __shared__ char smraw[];
    const bool isb = (*flg != 0.f);
    const int KC = (K + 31) & ~31;
    const int KP = KC + 8;                       // +8 bf16 pad -> 2-way banks (free)
    bf16*  kw_s = (bf16*)smraw;                  // [48][KP]
    float* lg_s = (float*)(smraw + 48 * KP * 2); // [4 waves][48][17]

    const int bc = blockIdx.y;
    const int b = bc / C, c = bc % C;
    const int tid = threadIdx.x, wave = tid >> 6, lane = tid & 63;
    const int quad = lane >> 4, l16 = lane & 15;
    const int p0 = blockIdx.x << 6;

    for (int i = tid; i < 48 * KC; i += 256) {
        int k = i % KC, j = i / KC;
        float v = (j < 36 && k < K) ? ldin(kw, (size_t)(c * 36 + j) * K + k, isb) : 0.f;
        kw_s[j * KP + k] = f2b(v);
    }
    __syncthreads();

    const int pw = p0 + (wave << 4);
    f32x4 acc[3] = {{0,0,0,0},{0,0,0,0},{0,0,0,0}};
    for (int kc = 0; kc < KC; kc += 32) {
        int kq = kc + quad * 8;
        short8 bfrag = {0,0,0,0,0,0,0,0};
        if (kq < K)
            bfrag = *(const short8*)&f[((size_t)b * H * W + pw + l16) * K + kq];
        #pragma unroll
        for (int t = 0; t < 3; ++t) {
            short8 afrag = *(const short8*)&kw_s[(t * 16 + l16) * KP + kq];
            acc[t] = __builtin_amdgcn_mfma_f32_16x16x32_bf16(afrag, bfrag, acc[t], 0, 0, 0);
        }
    }
    float* ls = lg_s + wave * 48 * 17;
    #pragma unroll
    for (int t = 0; t < 3; ++t)
        #pragma unroll
        for (int reg = 0; reg < 4; ++reg)
            ls[(t * 16 + (quad << 2) + reg) * 17 + l16] = acc[t][reg];
    __syncthreads();

    const int px_l = tid >> 2, g = tid & 3;
    const int p = p0 + px_l;
    const int h = p / W, w = p % W;
    const float* lp = lg_s + (px_l >> 4) * 48 * 17 + (px_l & 15);

    float lg[9];
    #pragma unroll
    for (int n = 0; n < 9; ++n)
        lg[n] = lp[(n * 4 + g) * 17] + ldin(kb, c * 36 + n * 4 + g, isb);

    float neigh[9];
    #pragma unroll
    for (int n = 0; n < 9; ++n) {
        int ih = h + n / 3 - 1; ih = min(max(ih, 0), H - 1);
        int iw = w + n % 3 - 1; iw = min(max(iw, 0), W - 1);
        neigh[n] = xext
            ? ldin(xlow, ((size_t)(b * C + c)) * H * W + (size_t)ih * W + iw, isb)
            : b2f(((const bf16*)xlow)[(((size_t)(b * H) + ih) * W + iw) * C + c]);
    }

    float mx = -1e30f;
    #pragma unroll
    for (int n = 0; n < 9; ++n) mx = fmaxf(mx, lg[n]);
    float se = 0.f, accv = 0.f;
    #pragma unroll
    for (int n = 0; n < 9; ++n) {
        float e = expf(lg[n] - mx);
        se += e;
        accv = fmaf(e, neigh[n], accv);
    }
    const int u = g >> 1, v = g & 1;
    size_t L = ((size_t)(w * 2 + v) * H + h) * 2 + u;    // torch permute(0,1,5,3,4,2)
    out[((size_t)b * 4 * H * W + L) * C + c] = f2b(accv / se);
}

// ---------------------------------------------------------------- memory bank: row-l2norm of mem
__global__ void memnorm_kernel(const void* __restrict__ mem, const float* __restrict__ flg,
                               float* __restrict__ mn) {
    bool isb = (*flg != 0.f);
    int s = threadIdx.x;          // 64 slots
    float v[32];
    float ss = 0.f;
    #pragma unroll
    for (int c = 0; c < 32; ++c) { v[c] = ldin(mem, s * 32 + c, isb); ss += v[c] * v[c]; }
    float inv = 1.f / fmaxf(sqrtf(ss), 1e-12f);
    #pragma unroll
    for (int c = 0; c < 32; ++c) mn[s * 32 + c] = v[c] * inv;
}

// ---------------------------------------------------------------- memory fusion (in place, channels-last bf16 ws)
__global__ __launch_bounds__(256, 2) void memfuse_kernel(
        bf16* __restrict__ x, const float* __restrict__ mn) {
    __shared__ float mns[64 * 32];
    for (int i = threadIdx.x; i < 64 * 32; i += blockDim.x) mns[i] = mn[i];
    __syncthreads();
    int idx = blockIdx.x * blockDim.x + threadIdx.x;   // over B*HW
    bf16* xp = x + (size_t)idx * 32;

    float feat[32];
    float ss = 0.f;
    #pragma unroll
    for (int c = 0; c < 32; ++c) { feat[c] = b2f(xp[c]); ss += feat[c] * feat[c]; }
    float inv = 1.f / fmaxf(sqrtf(ss), 1e-12f);

    float se = 0.f;
    float racc[32];
    #pragma unroll
    for (int c = 0; c < 32; ++c) racc[c] = 0.f;

    for (int s = 0; s < 64; ++s) {
        const float* mr = mns + s * 32;
        float dot = 0.f;
        #pragma unroll
        for (int c = 0; c < 32; ++c) dot = fmaf(feat[c], mr[c], dot);
        float e = expf(dot * inv);     // dot*inv in [-1,1] -> exp safe unshifted
        se += e;
        #pragma unroll
        for (int c = 0; c < 32; ++c) racc[c] = fmaf(e, mr[c], racc[c]);
    }
    float rse = 1.f / se;
    #pragma unroll
    for (int c = 0; c < 32; ++c)
        xp[c] = f2b(feat[c] + racc[c] * rse);
}

// ---------------------------------------------------------------- final 1x1 conv 32 -> 2 (x channels-last)
__global__ void final1x1_kernel(const bf16* __restrict__ x,
                                const void* __restrict__ fw, const void* __restrict__ fb,
                                const float* __restrict__ flg,
                                void* __restrict__ out, int HW) {
    bool isb = (*flg != 0.f);
    int idx = blockIdx.x * blockDim.x + threadIdx.x;   // over B*HW
    int b = idx / HW, p = idx % HW;
    const bf16* xp = x + (size_t)idx * 32;
    float a0 = ldin(fb, 0, isb), a1 = ldin(fb, 1, isb);
    #pragma unroll
    for (int c = 0; c < 32; ++c) {
        float v = b2f(xp[c]);
        a0 = fmaf(v, ldin(fw, c, isb), a0);
        a1 = fmaf(v, ldin(fw, 32 + c, isb), a1);
    }
    size_t i0 = (size_t)b * 2 * HW + p;
    size_t i1 = i0 + HW;
    if (isb) { ((bf16*)out)[i0] = f2b(a0); ((bf16*)out)[i1] = f2b(a1); }
    else     { ((float*)out)[i0] = a0;     ((float*)out)[i1] = a1; }
}

// ================================================================ host
extern "C" void kernel_launch(void* const* d_in, const int* in_sizes, int n_in,
                              void* d_out, int out_size, void* d_ws, size_t ws_size,
                              hipStream_t stream) {
    const void* x0_0 = d_in[0];
    const void* x1_0 = d_in[1];
    const void* x2_0 = d_in[2];
    const void* x3_0 = d_in[3];
    const void* c3_w1 = d_in[4];  const void* c3_b1 = d_in[5];  const void* c3_a1 = d_in[6];
    const void* c3_w2 = d_in[7];  const void* c3_b2 = d_in[8];  const void* c3_a2 = d_in[9];
    const void* c3_kw = d_in[10]; const void* c3_kb = d_in[11];
    const void* c2_w1 = d_in[12]; const void* c2_b1 = d_in[13]; const void* c2_a1 = d_in[14];
    const void* c2_w2 = d_in[15]; const void* c2_b2 = d_in[16]; const void* c2_a2 = d_in[17];
    const void* c2_kw = d_in[18]; const void* c2_kb = d_in[19];
    const void* c1_w1 = d_in[20]; const void* c1_b1 = d_in[21]; const void* c1_a1 = d_in[22];
    const void* c1_w2 = d_in[23]; const void* c1_b2 = d_in[24]; const void* c1_a2 = d_in[25];
    const void* c1_kw = d_in[26]; const void* c1_kb = d_in[27];
    const void* b21_w1 = d_in[28]; const void* b21_b1 = d_in[29];
    const void* b21_w2 = d_in[30]; const void* b21_b2 = d_in[31];
    const void* b12_w1 = d_in[32]; const void* b12_b1 = d_in[33];
    const void* b12_w2 = d_in[34]; const void* b12_b2 = d_in[35];
    const void* b03_w1 = d_in[36]; const void* b03_b1 = d_in[37];
    const void* b03_w2 = d_in[38]; const void* b03_b2 = d_in[39];
    const void* fin_w = d_in[40];  const void* fin_b = d_in[41];
    const void* memw  = d_in[42];
    (void)in_sizes; (void)n_in;

    const int TB = 256;
    auto blocks = [](int n) { return (n + 255) / 256; };

    const size_t NEED = 25165824 + 65536;
    if (ws_size < NEED) {
        diag_fill<<<blocks(out_size / 2), TB, 0, stream>>>(
            (unsigned int*)d_out, out_size / 2, (float)ws_size);
        return;
    }
    // Optional extra region: x0_0 channels-last copy ([2,256,256,32] bf16 = 8 MiB)
    // placed right after the 24 MiB arena when ws_size allows.
    const size_t NEED_X0 = 25165824 + 8388608 + 65536 + 256;
    const bool have_x0cl = (ws_size >= NEED_X0);

    // tail (>= 65,280B): [0,55296) b03 weight slot, [55296,63488) mn, [63488,+4) flg
    size_t tail = (ws_size - 65536) & ~(size_t)255;
    bf16*  wtail = (bf16*)((char*)d_ws + tail);
    float* mn    = (float*)((char*)d_ws + tail + 55296);
    float* flg   = (float*)((char*)d_ws + tail + 63488);

    // 24 MiB arena (12,582,912 bf16 elems), channels-last, verified live ranges.
    bf16* A = (bf16*)d_ws;
    bf16* x3up  = A + 0;         // [2,64,64,256]
    bf16* ctx3p = A + 2097152;   // [2,32,32,128]
    bf16* f3a   = A + 2359296;   // [2,32,32,128]
    bf16* f3b   = A + 2621440;   // [2,32,32,64]
    bf16* t2a   = A + 2097152;   // [2,64,64,128]
    bf16* x2cl  = A + 3145728;   // [2,64,64,128] cl copy of x2_0 (live: ->b21c1)
    bf16* x2_1  = A + 0;         // [2,64,64,128]
    bf16* ctx2  = A + 1048576;   // [2,64,64,64]
    bf16* f2a   = A + 1572864;   // [2,64,64,64]
    bf16* f2b   = A + 2097152;   // [2,64,64,32]
    bf16* x2up  = A + 2359296;   // [2,128,128,128]
    bf16* t1a   = A + 0;         // [2,128,128,64]
    bf16* x1cl  = A + 6995968;   // [2,128,128,64] cl copy of x1_0 (live: ->b12c1)
    bf16* x1_2  = A + 10485760;  // [2,128,128,64]
    bf16* ctx1  = A + 4194304;   // [2,128,128,32]
    bf16* f1a   = A + 5242880;   // [2,128,128,32]
    bf16* f1b   = A + 9437184;   // [2,128,128,16]
    bf16* x1up  = A + 0;         // [2,256,256,64]
    bf16* t0a   = A + 8388608;   // [2,256,256,32]
    bf16* x0_3  = A + 0;         // [2,256,256,32]
    bf16* wslot = A + 6553600;   // 442,368 elems max (b21_w1)
    bf16* x0cl  = A + 12582912;  // [2,256,256,32] (only if have_x0cl)

    detect_kernel<<<1, 64, 0, stream>>>((const unsigned int*)x0_0, flg);

    auto wpk = [&](const void* w, bf16* dst, int Cout, int Cin) {
        wpack_kernel<<<blocks(Cout * Cin * 9), TB, 0, stream>>>(w, flg, dst, Cout, Cin);
    };
    auto caun_shm = [](int K) {
        int KC = (K + 31) & ~31;
        return (size_t)(48 * (KC + 8) * 2 + 4 * 48 * 17 * 4);
    };
    auto cg = [](int H, int W, int Cout, int RT) {
        return dim3(W >> 4, H / (4 * RT), 2 * (Cout >> 4));
    };

    // ---- optional early transpose of x0_0 to channels-last (input-only dependency)
    if (have_x0cl)
        nchw2cl<<<2 * 1 * 1024, TB, 0, stream>>>(x0_0, flg, x0cl, 32, 65536);

    // ---- caun3: ctx = pool(x2_0) -> [2,32,32,128] cl
    pool2_cl<<<blocks(262144), TB, 0, stream>>>(x2_0, flg, ctx3p, 2, 128, 32, 32);
    wpk(c3_w1, wslot, 128, 128);
    conv3x3_cl<1><<<cg(32, 32, 128, 1), TB, 0, stream>>>(
        nullptr, 0, 0, ctx3p, 128, wslot, c3_b1, c3_a1, flg, f3a, 32, 32, 128, 2);
    wpk(c3_w2, wslot, 64, 128);
    conv3x3_cl<1><<<cg(32, 32, 64, 1), TB, 0, stream>>>(
        nullptr, 0, 0, f3a, 128, wslot, c3_b2, c3_a2, flg, f3b, 32, 32, 64, 2);
    caun_mfma<<<dim3(16, 512), TB, caun_shm(64), stream>>>(
        f3b, x3_0, 1, c3_kw, c3_kb, flg, x3up, 256, 64, 32, 32);

    // ---- block21: cat(x2_0 -> cl [128], x3up cl[256]) -> 128 -> 128 @64x64
    nchw2cl<<<2 * 4 * 64, TB, 0, stream>>>(x2_0, flg, x2cl, 128, 4096);
    wpk(b21_w1, wslot, 128, 384);
    conv3x3_cl<2><<<cg(64, 64, 128, 2), TB, 0, stream>>>(
        x2cl, 128, 0, x3up, 256, wslot, b21_b1, nullptr, flg, t2a, 64, 64, 128, 1);
    wpk(b21_w2, wslot, 128, 128);
    conv3x3_cl<2><<<cg(64, 64, 128, 2), TB, 0, stream>>>(
        nullptr, 0, 0, t2a, 128, wslot, b21_b2, nullptr, flg, x2_1, 64, 64, 128, 1);

    // ---- caun2: ctx = pool(x1_0) -> [2,64,64,64] cl
    pool2_cl<<<blocks(524288), TB, 0, stream>>>(x1_0, flg, ctx2, 2, 64, 64, 64);
    wpk(c2_w1, wslot, 64, 64);
    conv3x3_cl<2><<<cg(64, 64, 64, 2), TB, 0, stream>>>(
        nullptr, 0, 0, ctx2, 64, wslot, c2_b1, c2_a1, flg, f2a, 64, 64, 64, 2);
    wpk(c2_w2, wslot, 32, 64);
    conv3x3_cl<1><<<cg(64, 64, 32, 1), TB, 0, stream>>>(
        nullptr, 0, 0, f2a, 64, wslot, c2_b2, c2_a2, flg, f2b, 64, 64, 32, 2);
    caun_mfma<<<dim3(64, 256), TB, caun_shm(32), stream>>>(
        f2b, x2_1, 0, c2_kw, c2_kb, flg, x2up, 128, 32, 64, 64);

    // ---- block12: cat(x1_0 -> cl [64], x2up cl[128]) -> 64 -> 64 @128x128
    nchw2cl<<<2 * 2 * 256, TB, 0, stream>>>(x1_0, flg, x1cl, 64, 16384);
    wpk(b12_w1, wslot, 64, 192);
    conv3x3_cl<4><<<cg(128, 128, 64, 4), TB, 0, stream>>>(
        x1cl, 64, 0, x2up, 128, wslot, b12_b1, nullptr, flg, t1a, 128, 128, 64, 1);
    wpk(b12_w2, wslot, 64, 64);
    conv3x3_cl<4><<<cg(128, 128, 64, 4), TB, 0, stream>>>(
        nullptr, 0, 0, t1a, 64, wslot, b12_b2, nullptr, flg, x1_2, 128, 128, 64, 1);

    // ---- caun1: ctx = pool(x0_0) -> [2,128,128,32] cl
    pool2_cl<<<blocks(1048576), TB, 0, stream>>>(x0_0, flg, ctx1, 2, 32, 128, 128);
    wpk(c1_w1, wslot, 32, 32);
    conv3x3_cl<2><<<cg(128, 128, 32, 2), TB, 0, stream>>>(
        nullptr, 0, 0, ctx1, 32, wslot, c1_b1, c1_a1, flg, f1a, 128, 128, 32, 2);
    wpk(c1_w2, wslot, 16, 32);
    conv3x3_cl<2><<<cg(128, 128, 16, 2), TB, 0, stream>>>(
        nullptr, 0, 0, f1a, 32, wslot, c1_b2, c1_a2, flg, f1b, 128, 128, 16, 2);
    caun_mfma<<<dim3(256, 128), TB, caun_shm(16), stream>>>(
        f1b, x1_2, 0, c1_kw, c1_kb, flg, x1up, 64, 16, 128, 128);

    // ---- block03: cat(x0_0 [32], x1up cl[64]) -> 32 -> 32 @256x256  (weights in tail slot)
    wpk(b03_w1, wtail, 32, 96);
    if (have_x0cl) {
        conv3x3_cl<4><<<cg(256, 256, 32, 4), TB, 0, stream>>>(
            x0cl, 32, 0, x1up, 64, wtail, b03_b1, nullptr, flg, t0a, 256, 256, 32, 1);
    } else {
        conv3x3_cl<4><<<cg(256, 256, 32, 4), TB, 0, stream>>>(
            x0_0, 32, 1, x1up, 64, wtail, b03_b1, nullptr, flg, t0a, 256, 256, 32, 1);
    }
    wpk(b03_w2, wtail, 32, 32);
    conv3x3_cl<4><<<cg(256, 256, 32, 4), TB, 0, stream>>>(
        nullptr, 0, 0, t0a, 32, wtail, b03_b2, nullptr, flg, x0_3, 256, 256, 32, 1);

    // ---- memory-bank residual fusion (in place, cl) + final 1x1 conv -> [2,2,256,256]
    memnorm_kernel<<<1, 64, 0, stream>>>(memw, flg, mn);
    memfuse_kernel<<<512, TB, 0, stream>>>(x0_3, mn);
    final1x1_kernel<<<512, TB, 0, stream>>>(x0_3, fin_w, fin_b, flg, d_out, 256 * 256);
}